// Round 7
// baseline (292.962 us; speedup 1.0000x reference)
//
#include <hip/hip_runtime.h>

constexpr int Nn = 64, Tt = 512, Vv = 17, Oo = 64;
constexpr int TV  = Tt * Vv;      // 8704
constexpr int CTV = 3 * TV;       // 26112
constexpr float EPSf = 1e-5f;
constexpr int NB  = 512;          // cooperative grid
constexpr int BTV = 1088;         // 64*17

// exact floor(v/17) for v < ~60000
__device__ inline int div17(int v) { return (int)(((unsigned)v * 61681u) >> 20); }

__device__ inline double wred(double v) {
#pragma unroll
  for (int o = 32; o > 0; o >>= 1) v += __shfl_down(v, o, 64);
  return v;
}

// zero the barrier state (slots[512] + gen) every replay
__global__ void __launch_bounds__(256) kinit(int* __restrict__ bar) {
  for (int i = threadIdx.x; i < 520; i += 256) bar[i] = 0;
}

// two-level grid barrier: slot-store arrive, block-0 scan, gen publish.
// All 512 blocks MUST call with the same marker. Slots zeroed per replay.
__device__ inline void gridbar(int* slots, int* gen, int bid, int marker) {
  __syncthreads();
  if (threadIdx.x == 0) {
    __threadfence();   // make this block's global writes visible device-wide
    __hip_atomic_store(slots + bid, marker, __ATOMIC_RELEASE, __HIP_MEMORY_SCOPE_AGENT);
  }
  if (bid == 0) {
    for (int i = threadIdx.x; i < NB; i += 256) {
      while (__hip_atomic_load(slots + i, __ATOMIC_ACQUIRE, __HIP_MEMORY_SCOPE_AGENT) < marker)
        __builtin_amdgcn_s_sleep(1);
    }
    __syncthreads();
    if (threadIdx.x == 0)
      __hip_atomic_store(gen, marker, __ATOMIC_RELEASE, __HIP_MEMORY_SCOPE_AGENT);
  } else {
    if (threadIdx.x == 0) {
      while (__hip_atomic_load(gen, __ATOMIC_ACQUIRE, __HIP_MEMORY_SCOPE_AGENT) < marker)
        __builtin_amdgcn_s_sleep(1);
    }
  }
  __syncthreads();
}

__global__ void __launch_bounds__(256, 2) fused(
    const float* __restrict__ x,
    const float* __restrict__ w1, const float* __restrict__ b1,
    const float* __restrict__ w2, const float* __restrict__ b2,
    const float* __restrict__ cw, const float* __restrict__ cb,
    const float* __restrict__ cg_, const float* __restrict__ cbeta,
    const float* __restrict__ PA, const float* __restrict__ alpha,
    const float* __restrict__ c2w, const float* __restrict__ c2b,
    const float* __restrict__ bng, const float* __restrict__ bnb,
    const float* __restrict__ pw, const float* __restrict__ pb,
    const float* __restrict__ pg, const float* __restrict__ pbeta,
    float* __restrict__ out,
    int* __restrict__ barr, double* __restrict__ spart,
    float* __restrict__ a3part, float* __restrict__ Amat,
    double* __restrict__ ypart)
{
  __shared__ float smem[6528];     // A/B: l1t|l2t [17][68] x2 ; C: xs|ys [3][1088] x2
  __shared__ float As[289];
  __shared__ float coefs[512];
  __shared__ double dred[4][18];
  __shared__ double mom[18];
  __shared__ float sfl[2];
  float* l1t = smem;               // [17][68]
  float* l2t = smem + 1156;
  float* xs  = smem;               // [3][1088]
  float* ys  = smem + 3264;
  int* slots = barr;
  int* gen   = barr + NB;

  const int tid = threadIdx.x, bid = blockIdx.x;
  const int n = bid >> 3, ch = bid & 7;
  const int t0 = ch * 64;
  const int wv = tid >> 6;

  // folded weights (uniform)
  float u1[3], u2[3];
#pragma unroll
  for (int k = 0; k < 3; ++k) {
    float s1 = 0.f, s2 = 0.f;
#pragma unroll
    for (int c = 0; c < 3; ++c) { s1 += cw[c] * w1[c * 3 + k]; s2 += cw[c] * w2[c * 3 + k]; }
    u1[k] = s1; u2[k] = s2;
  }
  float d1 = 0.f, d2 = 0.f;
#pragma unroll
  for (int c = 0; c < 3; ++c) { d1 += b1[c] * cw[c]; d2 += b2[c] * cw[c]; }
  const float bb = cb[0];

  // ---------- Phase A: stage a1/g (transposed) for chunk rows + s-stat partials ----
  {
    const int nload = (ch == 7) ? 64 : 65;   // incl. boundary row for chain
    for (int idx = tid; idx < nload * 17; idx += 256) {
      int r = div17(idx), v = idx - r * 17;
      const float* xp = x + ((size_t)((n * Tt + t0 + r) * 17 + v)) * 3;
      float x0 = xp[0], x1 = xp[1], x2 = xp[2];
      float va1 = fmaf(x0, u1[0], fmaf(x1, u1[1], fmaf(x2, u1[2], d1)));
      float va2 = fmaf(x0, u2[0], fmaf(x1, u2[1], fmaf(x2, u2[2], d2)));
      l1t[v * 68 + r] = va1; l2t[v * 68 + r] = bb - va2;   // s_raw = l1[j] + l2[i]
    }
    __syncthreads();
    if (tid < 64) {                       // wave 0: one t-row each (only first 64 rows)
      float sA = 0.f, sG = 0.f, Q1 = 0.f, Q2 = 0.f;
#pragma unroll
      for (int v = 0; v < 17; ++v) {
        float a = l1t[v * 68 + tid], g = l2t[v * 68 + tid];
        sA += a; sG += g;
        Q1 = fmaf(a, a, Q1); Q2 = fmaf(g, g, Q2);
      }
      double st[5] = { (double)sA, (double)sG, (double)Q1, (double)Q2,
                       (double)sA * (double)sG };
#pragma unroll
      for (int s = 0; s < 5; ++s) {
        double r = wred(st[s]);
        if (tid == 0) spart[(size_t)bid * 5 + s] = r;
      }
    }
  }
  gridbar(slots, gen, bid, 1);

  // ---------- Phase B: redundant s-stat reduce -> scale/c0; chain -> a3part[e][bid] --
  {
    double v5[5];
#pragma unroll
    for (int s = 0; s < 5; ++s)
      v5[s] = spart[(size_t)tid * 5 + s] + spart[(size_t)(tid + 256) * 5 + s];
#pragma unroll
    for (int s = 0; s < 5; ++s) { double r = wred(v5[s]); if ((tid & 63) == 0) dred[wv][s] = r; }
    __syncthreads();
    if (tid == 0) {
      double S[5];
#pragma unroll
      for (int s = 0; s < 5; ++s) S[s] = dred[0][s] + dred[1][s] + dred[2][s] + dred[3][s];
      double cnt = (double)Nn * Tt * Vv * Vv;
      double mean = ((double)Vv * (S[0] + S[1])) / cnt;
      double m2   = ((double)Vv * (S[2] + S[3]) + 2.0 * S[4]) / cnt;
      double var  = m2 - mean * mean;
      double scale = (double)cg_[0] / sqrt(var + (double)EPSf);
      double shift = (double)cbeta[0] + scale * ((double)bb - mean);
      sfl[0] = (float)scale; sfl[1] = (float)(shift - scale * (double)bb);
    }
    __syncthreads();
    const float scale = sfl[0], c0 = sfl[1];
    const int last = (ch == 7) ? 63 : 64;   // chain values at cols 0..last
#pragma unroll 1
    for (int pass = 0; pass < 2; ++pass) {
      int e = tid + pass * 256;
      if (e < 289) {
        int i = div17(e), j = e - i * 17;
        const float* J = &l1t[j * 68];
        const float* I = &l2t[i * 68];
        float prev = fmaxf(fmaf(scale, J[0] + I[0], c0), 0.f);
        float acc = 0.f;
        for (int r = 1; r <= last; ++r) {
          float cur = fmaxf(fmaf(scale, J[r] + I[r], c0), 0.f);
          acc += fabsf(cur - prev); prev = cur;
        }
        a3part[(size_t)e * NB + bid] = acc;
      }
    }
  }
  gridbar(slots, gen, bid, 2);

  // ---------- Phase B2: blocks 0..288 reduce a3part row -> Amat[e] ----------
  if (bid < 289) {
    float sacc = 0.f;
#pragma unroll
    for (int j = tid; j < NB; j += 256) sacc += a3part[(size_t)bid * NB + j];
    double r = wred((double)sacc);
    if ((tid & 63) == 0) dred[wv][0] = r;
    __syncthreads();
    if (tid == 0) {
      float tot = (float)((dred[0][0] + dred[1][0] + dred[2][0] + dred[3][0]) * (1.0 / Nn));
      Amat[bid] = fmaf(alpha[bid], tot, PA[bid]);
    }
  }
  gridbar(slots, gen, bid, 3);

  // ---------- Phase C1: A->LDS, stage xs, compute ys + moment partials ----------
  {
    for (int e = tid; e < 289; e += 256) As[e] = Amat[e];
#pragma unroll
    for (int c = 0; c < 3; ++c) {
      const float4* src = (const float4*)(x + (size_t)n * CTV + (size_t)c * TV + ch * BTV);
      float4* dst = (float4*)(xs + c * BTV);
      for (int i = tid; i < 272; i += 256) dst[i] = src[i];
    }
    __syncthreads();
    float st[18];
#pragma unroll
    for (int s = 0; s < 18; ++s) st[s] = 0.f;
#pragma unroll
    for (int k = 0; k < 5; ++k) {
      int e = k * 256 + tid;
      if (e < BTV) {
        int tr = div17(e), v = e - tr * 17;
        float y0 = 0.f, y1 = 0.f, y2 = 0.f;
#pragma unroll
        for (int u = 0; u < 17; ++u) {
          float a = As[u * 17 + v];
          y0 = fmaf(xs[tr * 17 + u], a, y0);
          y1 = fmaf(xs[BTV + tr * 17 + u], a, y1);
          y2 = fmaf(xs[2 * BTV + tr * 17 + u], a, y2);
        }
        ys[e] = y0; ys[BTV + e] = y1; ys[2 * BTV + e] = y2;
        float x0 = xs[e], x1 = xs[BTV + e], x2 = xs[2 * BTV + e];
        st[0] += y0; st[1] += y1; st[2] += y2;
        st[3] = fmaf(y0, y0, st[3]); st[4] = fmaf(y0, y1, st[4]); st[5] = fmaf(y0, y2, st[5]);
        st[6] = fmaf(y1, y1, st[6]); st[7] = fmaf(y1, y2, st[7]); st[8] = fmaf(y2, y2, st[8]);
        st[9] += x0; st[10] += x1; st[11] += x2;
        st[12] = fmaf(x0, x0, st[12]); st[13] = fmaf(x0, x1, st[13]); st[14] = fmaf(x0, x2, st[14]);
        st[15] = fmaf(x1, x1, st[15]); st[16] = fmaf(x1, x2, st[16]); st[17] = fmaf(x2, x2, st[17]);
      }
    }
#pragma unroll
    for (int s = 0; s < 18; ++s) { double r = wred((double)st[s]); if ((tid & 63) == 0) dred[wv][s] = r; }
    __syncthreads();
    if (tid < 18)
      ypart[(size_t)bid * 18 + tid] = dred[0][tid] + dred[1][tid] + dred[2][tid] + dred[3][tid];
  }
  gridbar(slots, gen, bid, 4);

  // ---------- Phase C2: redundant moment reduce -> coefs -> fused output ----------
  {
    double v18[18];
#pragma unroll
    for (int s = 0; s < 18; ++s)
      v18[s] = ypart[(size_t)tid * 18 + s] + ypart[(size_t)(tid + 256) * 18 + s];
#pragma unroll
    for (int s = 0; s < 18; ++s) { double r = wred(v18[s]); if ((tid & 63) == 0) dred[wv][s] = r; }
    __syncthreads();
    if (tid < 18) mom[tid] = dred[0][tid] + dred[1][tid] + dred[2][tid] + dred[3][tid];
    __syncthreads();
    if (tid < 64) {
      int o = tid;
      const double cnt = (double)Nn * Tt * Vv;
      double my0 = mom[0] / cnt, my1 = mom[1] / cnt, my2 = mom[2] / cnt;
      double e00 = mom[3] / cnt, e01 = mom[4] / cnt, e02 = mom[5] / cnt;
      double e11 = mom[6] / cnt, e12 = mom[7] / cnt, e22 = mom[8] / cnt;
      double mx0 = mom[9] / cnt, mx1 = mom[10] / cnt, mx2 = mom[11] / cnt;
      double f00 = mom[12] / cnt, f01 = mom[13] / cnt, f02 = mom[14] / cnt;
      double f11 = mom[15] / cnt, f12 = mom[16] / cnt, f22 = mom[17] / cnt;
      double w0 = c2w[o * 3], w1_ = c2w[o * 3 + 1], w2_ = c2w[o * 3 + 2], bz = c2b[o];
      double wm = w0 * my0 + w1_ * my1 + w2_ * my2, mz = wm + bz;
      double Ez2 = w0 * w0 * e00 + 2 * w0 * w1_ * e01 + 2 * w0 * w2_ * e02
                 + w1_ * w1_ * e11 + 2 * w1_ * w2_ * e12 + w2_ * w2_ * e22
                 + 2 * bz * wm + bz * bz;
      double sz = (double)bng[o] / sqrt(Ez2 - mz * mz + (double)EPSf);
      double q0 = pw[o * 3], q1 = pw[o * 3 + 1], q2 = pw[o * 3 + 2], bp = pb[o];
      double qm = q0 * mx0 + q1 * mx1 + q2 * mx2, mp = qm + bp;
      double Ep2 = q0 * q0 * f00 + 2 * q0 * q1 * f01 + 2 * q0 * q2 * f02
                 + q1 * q1 * f11 + 2 * q1 * q2 * f12 + q2 * q2 * f22
                 + 2 * bp * qm + bp * bp;
      double sp = (double)pg[o] / sqrt(Ep2 - mp * mp + (double)EPSf);
      coefs[o * 8 + 0] = (float)(sz * w0); coefs[o * 8 + 1] = (float)(sz * w1_); coefs[o * 8 + 2] = (float)(sz * w2_);
      coefs[o * 8 + 3] = (float)(sp * q0); coefs[o * 8 + 4] = (float)(sp * q1); coefs[o * 8 + 5] = (float)(sp * q2);
      coefs[o * 8 + 6] = (float)(sz * (bz - mz) + (double)bnb[o] + sp * (bp - mp) + (double)pbeta[o]);
      coefs[o * 8 + 7] = 0.f;
    }
    __syncthreads();
    float* ob = out + (size_t)n * ((size_t)Oo * TV) + ch * BTV;
#pragma unroll 2
    for (int k = 0; k < 68; ++k) {          // 68*256 = 64 o * 272 float4
      int idx = k * 256 + tid;
      int o = div17(idx >> 4);
      int q = idx - o * 272, tq = q * 4;
      float4 y0 = *(const float4*)&ys[tq];
      float4 y1 = *(const float4*)&ys[BTV + tq];
      float4 y2 = *(const float4*)&ys[2 * BTV + tq];
      float4 x0 = *(const float4*)&xs[tq];
      float4 x1 = *(const float4*)&xs[BTV + tq];
      float4 x2 = *(const float4*)&xs[2 * BTV + tq];
      float a0 = coefs[o * 8 + 0], a1 = coefs[o * 8 + 1], a2 = coefs[o * 8 + 2];
      float p0 = coefs[o * 8 + 3], p1 = coefs[o * 8 + 4], p2 = coefs[o * 8 + 5];
      float be = coefs[o * 8 + 6];
      float4 r;
      r.x = fmaxf(fmaf(a0, y0.x, fmaf(a1, y1.x, fmaf(a2, y2.x, fmaf(p0, x0.x, fmaf(p1, x1.x, fmaf(p2, x2.x, be)))))), 0.f);
      r.y = fmaxf(fmaf(a0, y0.y, fmaf(a1, y1.y, fmaf(a2, y2.y, fmaf(p0, x0.y, fmaf(p1, x1.y, fmaf(p2, x2.y, be)))))), 0.f);
      r.z = fmaxf(fmaf(a0, y0.z, fmaf(a1, y1.z, fmaf(a2, y2.z, fmaf(p0, x0.z, fmaf(p1, x1.z, fmaf(p2, x2.z, be)))))), 0.f);
      r.w = fmaxf(fmaf(a0, y0.w, fmaf(a1, y1.w, fmaf(a2, y2.w, fmaf(p0, x0.w, fmaf(p1, x1.w, fmaf(p2, x2.w, be)))))), 0.f);
      *(float4*)(ob + (size_t)o * TV + tq) = r;
    }
  }
}

extern "C" void kernel_launch(void* const* d_in, const int* in_sizes, int n_in,
                              void* d_out, int out_size, void* d_ws, size_t ws_size,
                              hipStream_t stream)
{
  (void)in_sizes; (void)n_in; (void)out_size; (void)ws_size;
  const float* x     = (const float*)d_in[0];
  const float* w1    = (const float*)d_in[1];
  const float* b1    = (const float*)d_in[2];
  const float* w2    = (const float*)d_in[3];
  const float* b2    = (const float*)d_in[4];
  const float* cw    = (const float*)d_in[5];
  const float* cb    = (const float*)d_in[6];
  const float* cg_   = (const float*)d_in[7];
  const float* cbeta = (const float*)d_in[8];
  const float* PA    = (const float*)d_in[9];
  const float* alpha = (const float*)d_in[10];
  const float* c2w   = (const float*)d_in[11];
  const float* c2b   = (const float*)d_in[12];
  const float* bng   = (const float*)d_in[13];
  const float* bnb   = (const float*)d_in[14];
  const float* pw    = (const float*)d_in[15];
  const float* pb    = (const float*)d_in[16];
  const float* pg    = (const float*)d_in[17];
  const float* pbeta = (const float*)d_in[18];
  float* out = (float*)d_out;

  char* ws = (char*)d_ws;
  int*    barr   = (int*)(ws + 0);            // 520 ints -> pad 4096
  double* spart  = (double*)(ws + 4096);      // 512*5*8   = 20480 -> 24576
  float*  a3part = (float*)(ws + 24576);      // 289*512*4 = 591872 -> 616448
  float*  Amat   = (float*)(ws + 616448);     // 289*4 -> 617728
  double* ypart  = (double*)(ws + 617728);    // 512*18*8  = 73728 -> 691456

  hipLaunchKernelGGL(kinit, dim3(1), dim3(256), 0, stream, barr);

  void* args[] = {
    (void*)&x, (void*)&w1, (void*)&b1, (void*)&w2, (void*)&b2,
    (void*)&cw, (void*)&cb, (void*)&cg_, (void*)&cbeta,
    (void*)&PA, (void*)&alpha, (void*)&c2w, (void*)&c2b,
    (void*)&bng, (void*)&bnb, (void*)&pw, (void*)&pb, (void*)&pg, (void*)&pbeta,
    (void*)&out, (void*)&barr, (void*)&spart, (void*)&a3part, (void*)&Amat, (void*)&ypart
  };
  hipLaunchCooperativeKernel((const void*)fused, dim3(NB), dim3(256), args, 0, stream);
}

// Round 9
// 245.874 us; speedup vs baseline: 1.1915x; 1.1915x over previous
//
#include <hip/hip_runtime.h>

constexpr int Nn = 64, Tt = 512, Vv = 17, Oo = 64;
constexpr int TV  = Tt * Vv;      // 8704
constexpr int CTV = 3 * TV;       // 26112
constexpr float EPSf = 1e-5f;
constexpr int NB   = 512;         // coop grid
constexpr int NG   = 51;          // gram dim
constexpr int GSTR = 2688;        // gpart per-block stride (floats)
constexpr int NGE  = 2652;        // 51*51 + 51
constexpr int BTV  = 1088;        // 64*17
constexpr double FXS = 16777216.0;   // 2^24 fixed-point scale

__device__ inline int div17(int v) { return (int)(((unsigned)v * 61681u) >> 20); }

__device__ inline double wred(double v) {
#pragma unroll
  for (int o = 32; o > 0; o >>= 1) v += __shfl_down(v, o, 64);
  return v;
}

// zero barrier words + int64 accumulators each replay
__global__ void __launch_bounds__(256) kinit(int* __restrict__ barr, long long* __restrict__ acc) {
  for (int i = threadIdx.x; i < 520; i += 256) barr[i] = 0;
  for (int i = threadIdx.x; i < 304; i += 256) acc[i] = 0;
}

// two-level grid barrier with throttled polling
__device__ inline void gridbar(int* slots, int* gen, int bid, int marker) {
  __syncthreads();
  if (threadIdx.x == 0) {
    __threadfence();
    __hip_atomic_store(slots + bid, marker, __ATOMIC_RELEASE, __HIP_MEMORY_SCOPE_AGENT);
  }
  if (bid == 0) {
    for (int i = threadIdx.x; i < NB; i += 256) {
      while (__hip_atomic_load(slots + i, __ATOMIC_ACQUIRE, __HIP_MEMORY_SCOPE_AGENT) < marker)
        __builtin_amdgcn_s_sleep(8);
    }
    __syncthreads();
    if (threadIdx.x == 0)
      __hip_atomic_store(gen, marker, __ATOMIC_RELEASE, __HIP_MEMORY_SCOPE_AGENT);
  } else if (threadIdx.x == 0) {
    while (__hip_atomic_load(gen, __ATOMIC_ACQUIRE, __HIP_MEMORY_SCOPE_AGENT) < marker)
      __builtin_amdgcn_s_sleep(64);
  }
  __syncthreads();
}

// ========================= fused cooperative kernel (~30.9 KB LDS) =========================
__global__ void __launch_bounds__(256, 2) fused(
    const float* __restrict__ x,
    const float* __restrict__ w1, const float* __restrict__ b1,
    const float* __restrict__ w2, const float* __restrict__ b2,
    const float* __restrict__ cw, const float* __restrict__ cb,
    const float* __restrict__ cg_, const float* __restrict__ cbeta,
    const float* __restrict__ PA, const float* __restrict__ alpha,
    const float* __restrict__ c2w, const float* __restrict__ c2b,
    const float* __restrict__ bng, const float* __restrict__ bnb,
    const float* __restrict__ pw, const float* __restrict__ pb,
    const float* __restrict__ pg, const float* __restrict__ pbeta,
    float* __restrict__ out,
    int* __restrict__ barr, long long* __restrict__ accum,
    float* __restrict__ gpart, double* __restrict__ gramF)
{
  __shared__ float smem[6528];     // A/B: l1t[17*69] l2t[17*69] wr[64*56]; C: xs|ys
  __shared__ float As[289], Bh[289], rsA[17], coefs[512];
  __shared__ double dred[4][6];
  __shared__ double mom[18];
  __shared__ float sfl[2];
  float* l1t = smem;               // [17][69]
  float* l2t = smem + 1173;
  float* wr  = smem + 2346;        // [64][56]
  double* scrD = (double*)&smem[2348];  // phase-B scratch, floats[2348..5420]
  float* xs  = smem;               // phase C
  float* ys  = smem + 3264;
  int* slots = barr;
  int* gen   = barr + NB;
  long long* sstats  = accum;        // [5]
  long long* a3fixed = accum + 8;    // [289]

  const int tid = threadIdx.x, bid = blockIdx.x;
  const int n = bid >> 3, ch = bid & 7;
  const int t0 = ch * 64;

  float u1[3], u2[3];
#pragma unroll
  for (int k = 0; k < 3; ++k) {
    float s1 = 0.f, s2 = 0.f;
#pragma unroll
    for (int c = 0; c < 3; ++c) { s1 += cw[c] * w1[c * 3 + k]; s2 += cw[c] * w2[c * 3 + k]; }
    u1[k] = s1; u2[k] = s2;
  }
  float d1 = 0.f, d2 = 0.f;
#pragma unroll
  for (int c = 0; c < 3; ++c) { d1 += b1[c] * cw[c]; d2 += b2[c] * cw[c]; }
  const float bb = cb[0];

  // ============ Phase A: stage l1t/l2t + wr; stats->atomics; gram partials ============
  {
    const int nload = (ch == 7) ? 64 : 65;
    for (int idx = tid; idx < nload * 17; idx += 256) {
      int r = div17(idx), v = idx - r * 17;
      const float* xp = x + ((size_t)((n * Tt + t0 + r) * 17 + v)) * 3;
      float x0 = xp[0], x1 = xp[1], x2 = xp[2];
      float va1 = fmaf(x0, u1[0], fmaf(x1, u1[1], fmaf(x2, u1[2], d1)));
      float va2 = fmaf(x0, u2[0], fmaf(x1, u2[1], fmaf(x2, u2[2], d2)));
      l1t[v * 69 + r] = va1; l2t[v * 69 + r] = bb - va2;   // s_raw = l1[j] + l2[i]
    }
#pragma unroll
    for (int c = 0; c < 3; ++c) {
      const float4* src = (const float4*)(x + (size_t)n * CTV + (size_t)c * TV + ch * BTV);
      for (int i = tid; i < 272; i += 256) {
        float4 v = src[i];
        int p = i * 4;
        float vv[4] = { v.x, v.y, v.z, v.w };
#pragma unroll
        for (int k = 0; k < 4; ++k) {
          int pp = p + k; int t = div17(pp), u = pp - t * 17;
          wr[t * 56 + c * 17 + u] = vv[k];
        }
      }
    }
    for (int i = tid; i < 64 * 5; i += 256) { int t = i / 5, j = 51 + (i - t * 5); wr[t * 56 + j] = 0.f; }
    __syncthreads();

    if (tid < 64) {
      float sA = 0.f, sG = 0.f, Q1 = 0.f, Q2 = 0.f;
#pragma unroll
      for (int v = 0; v < 17; ++v) {
        float a = l1t[v * 69 + tid], g = l2t[v * 69 + tid];
        sA += a; sG += g;
        Q1 = fmaf(a, a, Q1); Q2 = fmaf(g, g, Q2);
      }
      double st[5] = { (double)sA, (double)sG, (double)Q1, (double)Q2,
                       (double)sA * (double)sG };
#pragma unroll
      for (int s = 0; s < 5; ++s) {
        double r = wred(st[s]);
        if (tid == 0)
          atomicAdd((unsigned long long*)&sstats[s], (unsigned long long)(long long)llrint(r * FXS));
      }
    }
    if (tid < 49) {
      const int r8 = (tid / 7) * 8, c8 = (tid - (tid / 7) * 7) * 8;
      float acc[8][8];
#pragma unroll
      for (int a = 0; a < 8; ++a)
#pragma unroll
        for (int b = 0; b < 8; ++b) acc[a][b] = 0.f;
      for (int t = 0; t < 64; ++t) {
        const float* row = &wr[t * 56];
        float4 ra0 = *(const float4*)(row + r8), ra1 = *(const float4*)(row + r8 + 4);
        float4 cb0 = *(const float4*)(row + c8), cb1 = *(const float4*)(row + c8 + 4);
        float ae[8] = { ra0.x, ra0.y, ra0.z, ra0.w, ra1.x, ra1.y, ra1.z, ra1.w };
        float be[8] = { cb0.x, cb0.y, cb0.z, cb0.w, cb1.x, cb1.y, cb1.z, cb1.w };
#pragma unroll
        for (int a = 0; a < 8; ++a)
#pragma unroll
          for (int b = 0; b < 8; ++b) acc[a][b] = fmaf(ae[a], be[b], acc[a][b]);
      }
      float* gp = gpart + (size_t)bid * GSTR;
#pragma unroll
      for (int a = 0; a < 8; ++a) {
        int j = r8 + a;
        if (j < NG) {
#pragma unroll
          for (int b = 0; b < 8; ++b) {
            int jp = c8 + b;
            if (jp < NG) gp[j * NG + jp] = acc[a][b];
          }
        }
      }
    }
    if (tid >= 128 && tid < 128 + NG) {
      int j = tid - 128;
      float m = 0.f;
      for (int t = 0; t < 64; ++t) m += wr[t * 56 + j];
      gpart[(size_t)bid * GSTR + NG * NG + j] = m;
    }
  }
  gridbar(slots, gen, bid, 1);

  // ============ Phase B: scale from atomics; gram finalize; chain -> a3 atomics ========
  {
    if (tid == 0) {
      double S[5];
#pragma unroll
      for (int s = 0; s < 5; ++s)
        S[s] = (double)__hip_atomic_load(&sstats[s], __ATOMIC_RELAXED, __HIP_MEMORY_SCOPE_AGENT) / FXS;
      double cnt = (double)Nn * Tt * Vv * Vv;
      double mean = ((double)Vv * (S[0] + S[1])) / cnt;
      double m2   = ((double)Vv * (S[2] + S[3]) + 2.0 * S[4]) / cnt;
      double var  = m2 - mean * mean;
      double scale = (double)cg_[0] / sqrt(var + (double)EPSf);
      double shift = (double)cbeta[0] + scale * ((double)bb - mean);
      sfl[0] = (float)scale; sfl[1] = (float)(shift - scale * (double)bb);
    }

    const int e0 = bid * 5 + (bid < 92 ? bid : 92);
    const int cnt = (bid < 92) ? 6 : 5;
    {
      const float* g1 = gpart + (size_t)tid * GSTR + e0;
      const float* g2 = gpart + (size_t)(tid + 256) * GSTR + e0;
      for (int k = 0; k < cnt; ++k)
        scrD[k * 256 + tid] = (double)g1[k] + (double)g2[k];
    }
    __syncthreads();
    {
      int wv = tid >> 6;
      for (int k = 0; k < cnt; ++k) {
        double r = wred(scrD[k * 256 + tid]);
        if ((tid & 63) == 0) dred[wv][k] = r;
      }
      __syncthreads();
      if (tid < cnt)
        gramF[e0 + tid] = dred[0][tid] + dred[1][tid] + dred[2][tid] + dred[3][tid];
    }

    const float scale = sfl[0], c0 = sfl[1];
    const int last = (ch == 7) ? 63 : 64;
#pragma unroll 1
    for (int pass = 0; pass < 2; ++pass) {
      int e = tid + pass * 256;
      if (e < 289) {
        int i = div17(e), j = e - i * 17;
        const float* J = &l1t[j * 69];
        const float* I = &l2t[i * 69];
        float prev = fmaxf(fmaf(scale, J[0] + I[0], c0), 0.f);
        float acc = 0.f;
        for (int r = 1; r <= last; ++r) {
          float cur = fmaxf(fmaf(scale, J[r] + I[r], c0), 0.f);
          acc += fabsf(cur - prev); prev = cur;
        }
        atomicAdd((unsigned long long*)&a3fixed[e],
                  (unsigned long long)(long long)llrint((double)acc * FXS));
      }
    }
  }
  gridbar(slots, gen, bid, 2);

  // ============ Phase C: A, moments (gram from global), coefs, y, output ============
  {
#pragma unroll
    for (int c = 0; c < 3; ++c) {
      const float4* src = (const float4*)(x + (size_t)n * CTV + (size_t)c * TV + ch * BTV);
      float4* dst = (float4*)(xs + c * BTV);
      for (int i = tid; i < 272; i += 256) dst[i] = src[i];
    }
    for (int e = tid; e < 289; e += 256) {
      long long raw = __hip_atomic_load(&a3fixed[e], __ATOMIC_RELAXED, __HIP_MEMORY_SCOPE_AGENT);
      float a3 = (float)((double)raw * (1.0 / FXS) * (1.0 / Nn));
      As[e] = fmaf(alpha[e], a3, PA[e]);
    }
    __syncthreads();

    for (int k = tid; k < 289; k += 256) {
      int u = div17(k), up = k - u * 17;
      float s = 0.f;
#pragma unroll
      for (int v = 0; v < 17; ++v) s = fmaf(As[u * 17 + v], As[up * 17 + v], s);
      Bh[k] = s;
    }
    if (tid < 17) {
      float s = 0.f;
#pragma unroll
      for (int v = 0; v < 17; ++v) s += As[tid * 17 + v];
      rsA[tid] = s;
    }
    __syncthreads();

    {
      const int pc0[6] = {0, 0, 0, 1, 1, 2};
      const int pc1[6] = {0, 1, 2, 1, 2, 2};
      if (tid < 192) {
        int p = tid >> 5, r = tid & 31;
        int c = pc0[p], cp = pc1[p];
        double s = 0.0;
        for (int k = r; k < 289; k += 32) {
          int u = div17(k), up = k - u * 17;
          s += gramF[(c * 17 + u) * NG + cp * 17 + up] * (double)Bh[k];
        }
#pragma unroll
        for (int off = 16; off > 0; off >>= 1) s += __shfl_down(s, off, 32);
        if (r == 0) mom[3 + p] = s;
      } else if (tid < 198) {
        int p = tid - 192; const int c = pc0[p], cp = pc1[p];
        double s = 0.0;
#pragma unroll
        for (int u = 0; u < 17; ++u) s += gramF[(c * 17 + u) * NG + cp * 17 + u];
        mom[12 + p] = s;
      } else if (tid < 201) {
        int c = tid - 198; double s = 0.0;
#pragma unroll
        for (int u = 0; u < 17; ++u) s += gramF[NG * NG + c * 17 + u] * (double)rsA[u];
        mom[c] = s;
      } else if (tid < 204) {
        int c = tid - 201; double s = 0.0;
#pragma unroll
        for (int u = 0; u < 17; ++u) s += gramF[NG * NG + c * 17 + u];
        mom[9 + c] = s;
      }
    }
    __syncthreads();

    if (tid < 64) {
      int o = tid;
      const double cnt = (double)Nn * Tt * Vv;
      double my0 = mom[0] / cnt, my1 = mom[1] / cnt, my2 = mom[2] / cnt;
      double e00 = mom[3] / cnt, e01 = mom[4] / cnt, e02 = mom[5] / cnt;
      double e11 = mom[6] / cnt, e12 = mom[7] / cnt, e22 = mom[8] / cnt;
      double mx0 = mom[9] / cnt, mx1 = mom[10] / cnt, mx2 = mom[11] / cnt;
      double f00 = mom[12] / cnt, f01 = mom[13] / cnt, f02 = mom[14] / cnt;
      double f11 = mom[15] / cnt, f12 = mom[16] / cnt, f22 = mom[17] / cnt;
      double w0 = c2w[o * 3], w1_ = c2w[o * 3 + 1], w2_ = c2w[o * 3 + 2], bz = c2b[o];
      double wm = w0 * my0 + w1_ * my1 + w2_ * my2, mz = wm + bz;
      double Ez2 = w0 * w0 * e00 + 2 * w0 * w1_ * e01 + 2 * w0 * w2_ * e02
                 + w1_ * w1_ * e11 + 2 * w1_ * w2_ * e12 + w2_ * w2_ * e22
                 + 2 * bz * wm + bz * bz;
      double sz = (double)bng[o] / sqrt(Ez2 - mz * mz + (double)EPSf);
      double q0 = pw[o * 3], q1 = pw[o * 3 + 1], q2 = pw[o * 3 + 2], bp = pb[o];
      double qm = q0 * mx0 + q1 * mx1 + q2 * mx2, mp = qm + bp;
      double Ep2 = q0 * q0 * f00 + 2 * q0 * q1 * f01 + 2 * q0 * q2 * f02
                 + q1 * q1 * f11 + 2 * q1 * q2 * f12 + q2 * q2 * f22
                 + 2 * bp * qm + bp * bp;
      double sp = (double)pg[o] / sqrt(Ep2 - mp * mp + (double)EPSf);
      coefs[o * 8 + 0] = (float)(sz * w0); coefs[o * 8 + 1] = (float)(sz * w1_); coefs[o * 8 + 2] = (float)(sz * w2_);
      coefs[o * 8 + 3] = (float)(sp * q0); coefs[o * 8 + 4] = (float)(sp * q1); coefs[o * 8 + 5] = (float)(sp * q2);
      coefs[o * 8 + 6] = (float)(sz * (bz - mz) + (double)bnb[o] + sp * (bp - mp) + (double)pbeta[o]);
      coefs[o * 8 + 7] = 0.f;
    }
#pragma unroll
    for (int k = 0; k < 5; ++k) {
      int e = k * 256 + tid;
      if (e < BTV) {
        int tr = div17(e), v = e - tr * 17;
        float y0 = 0.f, y1 = 0.f, y2 = 0.f;
#pragma unroll
        for (int u = 0; u < 17; ++u) {
          float a = As[u * 17 + v];
          y0 = fmaf(xs[tr * 17 + u], a, y0);
          y1 = fmaf(xs[BTV + tr * 17 + u], a, y1);
          y2 = fmaf(xs[2 * BTV + tr * 17 + u], a, y2);
        }
        ys[e] = y0; ys[BTV + e] = y1; ys[2 * BTV + e] = y2;
      }
    }
    __syncthreads();

    float* ob = out + (size_t)n * ((size_t)Oo * TV) + ch * BTV;
#pragma unroll 2
    for (int k = 0; k < 68; ++k) {
      int idx = k * 256 + tid;
      int o = div17(idx >> 4);
      int q = idx - o * 272, tq = q * 4;
      float4 y0 = *(const float4*)&ys[tq];
      float4 y1 = *(const float4*)&ys[BTV + tq];
      float4 y2 = *(const float4*)&ys[2 * BTV + tq];
      float4 x0 = *(const float4*)&xs[tq];
      float4 x1 = *(const float4*)&xs[BTV + tq];
      float4 x2 = *(const float4*)&xs[2 * BTV + tq];
      float a0 = coefs[o * 8 + 0], a1 = coefs[o * 8 + 1], a2 = coefs[o * 8 + 2];
      float p0 = coefs[o * 8 + 3], p1 = coefs[o * 8 + 4], p2 = coefs[o * 8 + 5];
      float be = coefs[o * 8 + 6];
      float4 r;
      r.x = fmaxf(fmaf(a0, y0.x, fmaf(a1, y1.x, fmaf(a2, y2.x, fmaf(p0, x0.x, fmaf(p1, x1.x, fmaf(p2, x2.x, be)))))), 0.f);
      r.y = fmaxf(fmaf(a0, y0.y, fmaf(a1, y1.y, fmaf(a2, y2.y, fmaf(p0, x0.y, fmaf(p1, x1.y, fmaf(p2, x2.y, be)))))), 0.f);
      r.z = fmaxf(fmaf(a0, y0.z, fmaf(a1, y1.z, fmaf(a2, y2.z, fmaf(p0, x0.z, fmaf(p1, x1.z, fmaf(p2, x2.z, be)))))), 0.f);
      r.w = fmaxf(fmaf(a0, y0.w, fmaf(a1, y1.w, fmaf(a2, y2.w, fmaf(p0, x0.w, fmaf(p1, x1.w, fmaf(p2, x2.w, be)))))), 0.f);
      *(float4*)(ob + (size_t)o * TV + tq) = r;
    }
  }
}

// ========================= fallback path (r6, verified 89.2 us) =========================
__global__ void __launch_bounds__(256) fk1(
    const float* __restrict__ x,
    const float* __restrict__ w1, const float* __restrict__ b1,
    const float* __restrict__ w2, const float* __restrict__ b2,
    const float* __restrict__ cw, const float* __restrict__ cb,
    double* __restrict__ spart, float* __restrict__ gpart)
{
  __shared__ float wr[64 * 56];
  __shared__ float xsA[64 * 51];
  __shared__ double dred[4][5];
  const int tid = threadIdx.x, bid = blockIdx.x;
  const int n = bid >> 3, ch = bid & 7;
  {
    const float4* src = (const float4*)(x + (size_t)bid * 3264);
    float4* dst = (float4*)xsA;
    for (int i = tid; i < 816; i += 256) dst[i] = src[i];
  }
#pragma unroll
  for (int c = 0; c < 3; ++c) {
    const float4* src = (const float4*)(x + (size_t)n * CTV + (size_t)c * TV + ch * BTV);
    for (int i = tid; i < 272; i += 256) {
      float4 v = src[i];
      int p = i * 4;
      float vv[4] = { v.x, v.y, v.z, v.w };
#pragma unroll
      for (int k = 0; k < 4; ++k) {
        int pp = p + k; int t = div17(pp), u = pp - t * 17;
        wr[t * 56 + c * 17 + u] = vv[k];
      }
    }
  }
  for (int i = tid; i < 64 * 5; i += 256) { int t = i / 5, j = 51 + (i - t * 5); wr[t * 56 + j] = 0.f; }
  __syncthreads();
  float u1[3], u2[3];
#pragma unroll
  for (int k = 0; k < 3; ++k) {
    float s1 = 0.f, s2 = 0.f;
#pragma unroll
    for (int c = 0; c < 3; ++c) { s1 += cw[c] * w1[c * 3 + k]; s2 += cw[c] * w2[c * 3 + k]; }
    u1[k] = s1; u2[k] = s2;
  }
  float d1 = 0.f, d2 = 0.f;
#pragma unroll
  for (int c = 0; c < 3; ++c) { d1 += b1[c] * cw[c]; d2 += b2[c] * cw[c]; }
  const float bb = cb[0];
  if (tid < 49) {
    const int r8 = (tid / 7) * 8, c8 = (tid - (tid / 7) * 7) * 8;
    float acc[8][8];
#pragma unroll
    for (int a = 0; a < 8; ++a)
#pragma unroll
      for (int b = 0; b < 8; ++b) acc[a][b] = 0.f;
    for (int t = 0; t < 64; ++t) {
      const float* row = &wr[t * 56];
      float4 ra0 = *(const float4*)(row + r8), ra1 = *(const float4*)(row + r8 + 4);
      float4 cb0 = *(const float4*)(row + c8), cb1 = *(const float4*)(row + c8 + 4);
      float ae[8] = { ra0.x, ra0.y, ra0.z, ra0.w, ra1.x, ra1.y, ra1.z, ra1.w };
      float be[8] = { cb0.x, cb0.y, cb0.z, cb0.w, cb1.x, cb1.y, cb1.z, cb1.w };
#pragma unroll
      for (int a = 0; a < 8; ++a)
#pragma unroll
        for (int b = 0; b < 8; ++b) acc[a][b] = fmaf(ae[a], be[b], acc[a][b]);
    }
    float* gp = gpart + (size_t)bid * GSTR;
#pragma unroll
    for (int a = 0; a < 8; ++a) {
      int j = r8 + a;
      if (j < NG) {
#pragma unroll
        for (int b = 0; b < 8; ++b) {
          int jp = c8 + b;
          if (jp < NG) gp[j * NG + jp] = acc[a][b];
        }
      }
    }
  }
  double st[5] = {0, 0, 0, 0, 0};
  if (tid >= 64 && tid < 128) {
    const float* rp = &xsA[(tid - 64) * 51];
    float A = 0.f, G = 0.f, Q1 = 0.f, Q2 = 0.f;
#pragma unroll
    for (int v = 0; v < 17; ++v) {
      float x0 = rp[v * 3], x1 = rp[v * 3 + 1], x2 = rp[v * 3 + 2];
      float va1 = fmaf(x0, u1[0], fmaf(x1, u1[1], fmaf(x2, u1[2], d1)));
      float va2 = fmaf(x0, u2[0], fmaf(x1, u2[1], fmaf(x2, u2[2], d2)));
      float g = bb - va2;
      A += va1; G += g;
      Q1 = fmaf(va1, va1, Q1); Q2 = fmaf(g, g, Q2);
    }
    st[0] = A; st[1] = G; st[2] = Q1; st[3] = Q2; st[4] = (double)A * (double)G;
  }
  if (tid >= 128 && tid < 128 + NG) {
    int j = tid - 128;
    float m = 0.f;
    for (int t = 0; t < 64; ++t) m += wr[t * 56 + j];
    gpart[(size_t)bid * GSTR + NG * NG + j] = m;
  }
  {
    int wv = tid >> 6;
#pragma unroll
    for (int s = 0; s < 5; ++s) { double r = wred(st[s]); if ((tid & 63) == 0) dred[wv][s] = r; }
  }
  __syncthreads();
  if (tid < 5)
    spart[(size_t)bid * 5 + tid] = dred[0][tid] + dred[1][tid] + dred[2][tid] + dred[3][tid];
}

__global__ void __launch_bounds__(256) fk2(
    const float* __restrict__ x, const double* __restrict__ spart,
    const float* __restrict__ gpart,
    const float* __restrict__ w1, const float* __restrict__ b1,
    const float* __restrict__ w2, const float* __restrict__ b2,
    const float* __restrict__ cw, const float* __restrict__ cb,
    const float* __restrict__ cg_, const float* __restrict__ cbeta,
    float* __restrict__ a3part, double* __restrict__ gramF)
{
  __shared__ float l1t[17 * 260];
  __shared__ float l2t[17 * 260];
  __shared__ float segsum[289 * 4];
  __shared__ double dred[4][21];
  __shared__ float sfl[2];
  const int tid = threadIdx.x;
  const int h = blockIdx.x, n = blockIdx.y;
  const int jb = n * 2 + h;
  const int t0 = h * 256;
  const int wv = tid >> 6;
  {
    double v5[5];
#pragma unroll
    for (int s = 0; s < 5; ++s)
      v5[s] = spart[(size_t)tid * 5 + s] + spart[(size_t)(tid + 256) * 5 + s];
#pragma unroll
    for (int s = 0; s < 5; ++s) { double r = wred(v5[s]); if ((tid & 63) == 0) dred[wv][s] = r; }
  }
  __syncthreads();
  if (tid == 0) {
    double S[5];
#pragma unroll
    for (int s = 0; s < 5; ++s) S[s] = dred[0][s] + dred[1][s] + dred[2][s] + dred[3][s];
    double cnt = (double)Nn * Tt * Vv * Vv;
    double mean = ((double)Vv * (S[0] + S[1])) / cnt;
    double m2   = ((double)Vv * (S[2] + S[3]) + 2.0 * S[4]) / cnt;
    double var  = m2 - mean * mean;
    double scale = (double)cg_[0] / sqrt(var + (double)EPSf);
    double shift = (double)cbeta[0] + scale * ((double)cb[0] - mean);
    sfl[0] = (float)scale; sfl[1] = (float)(shift - scale * (double)cb[0]);
  }
  __syncthreads();
  {
    int e0 = jb * 21;
    double gv[21];
    const float* g1 = gpart + (size_t)tid * GSTR + e0;
    const float* g2 = gpart + (size_t)(tid + 256) * GSTR + e0;
#pragma unroll
    for (int k = 0; k < 21; ++k) gv[k] = (double)g1[k] + (double)g2[k];
#pragma unroll
    for (int k = 0; k < 21; ++k) { double r = wred(gv[k]); if ((tid & 63) == 0) dred[wv][k] = r; }
    __syncthreads();
    if (tid < 21 && e0 + tid < NGE)
      gramF[e0 + tid] = dred[0][tid] + dred[1][tid] + dred[2][tid] + dred[3][tid];
  }
  float u1[3], u2[3];
#pragma unroll
  for (int k = 0; k < 3; ++k) {
    float s1 = 0.f, s2 = 0.f;
#pragma unroll
    for (int c = 0; c < 3; ++c) { s1 += cw[c] * w1[c * 3 + k]; s2 += cw[c] * w2[c * 3 + k]; }
    u1[k] = s1; u2[k] = s2;
  }
  float d1 = 0.f, d2 = 0.f;
#pragma unroll
  for (int c = 0; c < 3; ++c) { d1 += b1[c] * cw[c]; d2 += b2[c] * cw[c]; }
  const float bb = cb[0];
  const int nst = (h == 0) ? 257 : 256;
  const float* xb = x + ((size_t)(n * Tt + t0)) * 51;
  for (int idx = tid; idx < nst * 17; idx += 256) {
    int r = div17(idx), v = idx - r * 17;
    const float* xp = xb + idx * 3;
    float x0 = xp[0], x1 = xp[1], x2 = xp[2];
    float va1 = fmaf(x0, u1[0], fmaf(x1, u1[1], fmaf(x2, u1[2], d1)));
    float va2 = fmaf(x0, u2[0], fmaf(x1, u2[1], fmaf(x2, u2[2], d2)));
    l1t[v * 260 + r] = va1; l2t[v * 260 + r] = bb - va2;
  }
  __syncthreads();
  {
    const float scale = sfl[0], c0 = sfl[1];
    for (int task = tid; task < 289 * 4; task += 256) {
      int e = task >> 2, s = task & 3;
      int i = div17(e), j = e - i * 17;
      int ts = s * 64;
      bool hasb = !(h == 1 && s == 3);
      const float* J = &l1t[j * 260];
      const float* I = &l2t[i * 260];
      float prev = fmaxf(fmaf(scale, J[ts] + I[ts], c0), 0.f);
      float acc = 0.f;
#pragma unroll 4
      for (int q = 0; q < 16; ++q) {
        float4 a4 = *(const float4*)(J + ts + q * 4);
        float4 b4 = *(const float4*)(I + ts + q * 4);
        float z0 = fmaxf(fmaf(scale, a4.x + b4.x, c0), 0.f);
        float z1 = fmaxf(fmaf(scale, a4.y + b4.y, c0), 0.f);
        float z2 = fmaxf(fmaf(scale, a4.z + b4.z, c0), 0.f);
        float z3 = fmaxf(fmaf(scale, a4.w + b4.w, c0), 0.f);
        if (q > 0) acc += fabsf(z0 - prev);
        acc += fabsf(z1 - z0) + fabsf(z2 - z1) + fabsf(z3 - z2);
        prev = z3;
      }
      if (hasb) {
        float zb = fmaxf(fmaf(scale, J[ts + 64] + I[ts + 64], c0), 0.f);
        acc += fabsf(zb - prev);
      }
      segsum[e * 4 + s] = acc;
    }
  }
  __syncthreads();
  for (int e = tid; e < 289; e += 256) {
    float s = (segsum[e * 4] + segsum[e * 4 + 1]) + (segsum[e * 4 + 2] + segsum[e * 4 + 3]);
    a3part[(size_t)jb * 289 + e] = s;
  }
}

__global__ void __launch_bounds__(256, 2) fk3(
    const float* __restrict__ x,
    const float* __restrict__ PA, const float* __restrict__ alpha,
    const float* __restrict__ a3part, const double* __restrict__ gramF,
    const float* __restrict__ c2w, const float* __restrict__ c2b,
    const float* __restrict__ bng, const float* __restrict__ bnb,
    const float* __restrict__ pw, const float* __restrict__ pb,
    const float* __restrict__ pg, const float* __restrict__ pbeta,
    float* __restrict__ out)
{
  __shared__ float xs[3 * BTV], ys[3 * BTV];
  __shared__ float As[289], Bh[289], rsA[17], coefs[512];
  __shared__ double mom[18];
  const int tid = threadIdx.x, bid = blockIdx.x;
  const int n = bid >> 3, ch = bid & 7;
  const int t0c = ch * BTV;
#pragma unroll
  for (int c = 0; c < 3; ++c) {
    const float4* src = (const float4*)(x + (size_t)n * CTV + (size_t)c * TV + t0c);
    float4* dst = (float4*)(xs + c * BTV);
    for (int i = tid; i < 272; i += 256) dst[i] = src[i];
  }
  for (int e = tid; e < 289; e += 256) {
    float acc = 0.f;
#pragma unroll 4
    for (int j = 0; j < 128; ++j) acc += a3part[(size_t)j * 289 + e];
    As[e] = fmaf(alpha[e], acc * (1.0f / Nn), PA[e]);
  }
  __syncthreads();
  for (int k = tid; k < 289; k += 256) {
    int u = div17(k), up = k - u * 17;
    float s = 0.f;
#pragma unroll
    for (int v = 0; v < 17; ++v) s = fmaf(As[u * 17 + v], As[up * 17 + v], s);
    Bh[k] = s;
  }
  if (tid < 17) {
    float s = 0.f;
#pragma unroll
    for (int v = 0; v < 17; ++v) s += As[tid * 17 + v];
    rsA[tid] = s;
  }
  __syncthreads();
  {
    const int pc0[6] = {0, 0, 0, 1, 1, 2};
    const int pc1[6] = {0, 1, 2, 1, 2, 2};
    if (tid < 192) {
      int p = tid >> 5, r = tid & 31;
      int c = pc0[p], cp = pc1[p];
      double s = 0.0;
      for (int k = r; k < 289; k += 32) {
        int u = div17(k), up = k - u * 17;
        s += gramF[(c * 17 + u) * NG + cp * 17 + up] * (double)Bh[k];
      }
#pragma unroll
      for (int off = 16; off > 0; off >>= 1) s += __shfl_down(s, off, 32);
      if (r == 0) mom[3 + p] = s;
    } else if (tid < 198) {
      int p = tid - 192; const int c = pc0[p], cp = pc1[p];
      double s = 0.0;
#pragma unroll
      for (int u = 0; u < 17; ++u) s += gramF[(c * 17 + u) * NG + cp * 17 + u];
      mom[12 + p] = s;
    } else if (tid < 201) {
      int c = tid - 198; double s = 0.0;
#pragma unroll
      for (int u = 0; u < 17; ++u) s += gramF[NG * NG + c * 17 + u] * (double)rsA[u];
      mom[c] = s;
    } else if (tid < 204) {
      int c = tid - 201; double s = 0.0;
#pragma unroll
      for (int u = 0; u < 17; ++u) s += gramF[NG * NG + c * 17 + u];
      mom[9 + c] = s;
    }
  }
  __syncthreads();
  if (tid < 64) {
    int o = tid;
    const double cnt = (double)Nn * Tt * Vv;
    double my0 = mom[0] / cnt, my1 = mom[1] / cnt, my2 = mom[2] / cnt;
    double e00 = mom[3] / cnt, e01 = mom[4] / cnt, e02 = mom[5] / cnt;
    double e11 = mom[6] / cnt, e12 = mom[7] / cnt, e22 = mom[8] / cnt;
    double mx0 = mom[9] / cnt, mx1 = mom[10] / cnt, mx2 = mom[11] / cnt;
    double f00 = mom[12] / cnt, f01 = mom[13] / cnt, f02 = mom[14] / cnt;
    double f11 = mom[15] / cnt, f12 = mom[16] / cnt, f22 = mom[17] / cnt;
    double w0 = c2w[o * 3], w1_ = c2w[o * 3 + 1], w2_ = c2w[o * 3 + 2], bz = c2b[o];
    double wm = w0 * my0 + w1_ * my1 + w2_ * my2, mz = wm + bz;
    double Ez2 = w0 * w0 * e00 + 2 * w0 * w1_ * e01 + 2 * w0 * w2_ * e02
               + w1_ * w1_ * e11 + 2 * w1_ * w2_ * e12 + w2_ * w2_ * e22
               + 2 * bz * wm + bz * bz;
    double sz = (double)bng[o] / sqrt(Ez2 - mz * mz + (double)EPSf);
    double q0 = pw[o * 3], q1 = pw[o * 3 + 1], q2 = pw[o * 3 + 2], bp = pb[o];
    double qm = q0 * mx0 + q1 * mx1 + q2 * mx2, mp = qm + bp;
    double Ep2 = q0 * q0 * f00 + 2 * q0 * q1 * f01 + 2 * q0 * q2 * f02
               + q1 * q1 * f11 + 2 * q1 * q2 * f12 + q2 * q2 * f22
               + 2 * bp * qm + bp * bp;
    double sp = (double)pg[o] / sqrt(Ep2 - mp * mp + (double)EPSf);
    coefs[o * 8 + 0] = (float)(sz * w0); coefs[o * 8 + 1] = (float)(sz * w1_); coefs[o * 8 + 2] = (float)(sz * w2_);
    coefs[o * 8 + 3] = (float)(sp * q0); coefs[o * 8 + 4] = (float)(sp * q1); coefs[o * 8 + 5] = (float)(sp * q2);
    coefs[o * 8 + 6] = (float)(sz * (bz - mz) + (double)bnb[o] + sp * (bp - mp) + (double)pbeta[o]);
    coefs[o * 8 + 7] = 0.f;
  }
#pragma unroll
  for (int k = 0; k < 5; ++k) {
    int e = k * 256 + tid;
    if (e < BTV) {
      int tr = div17(e), v = e - tr * 17;
      float y0 = 0.f, y1 = 0.f, y2 = 0.f;
#pragma unroll
      for (int u = 0; u < 17; ++u) {
        float a = As[u * 17 + v];
        y0 = fmaf(xs[tr * 17 + u], a, y0);
        y1 = fmaf(xs[BTV + tr * 17 + u], a, y1);
        y2 = fmaf(xs[2 * BTV + tr * 17 + u], a, y2);
      }
      ys[e] = y0; ys[BTV + e] = y1; ys[2 * BTV + e] = y2;
    }
  }
  __syncthreads();
  float* ob = out + (size_t)n * ((size_t)Oo * TV) + t0c;
#pragma unroll 2
  for (int k = 0; k < 68; ++k) {
    int idx = k * 256 + tid;
    int o = div17(idx >> 4);
    int q = idx - o * 272, tq = q * 4;
    float4 y0 = *(const float4*)&ys[tq];
    float4 y1 = *(const float4*)&ys[BTV + tq];
    float4 y2 = *(const float4*)&ys[2 * BTV + tq];
    float4 x0 = *(const float4*)&xs[tq];
    float4 x1 = *(const float4*)&xs[BTV + tq];
    float4 x2 = *(const float4*)&xs[2 * BTV + tq];
    float a0 = coefs[o * 8 + 0], a1 = coefs[o * 8 + 1], a2 = coefs[o * 8 + 2];
    float p0 = coefs[o * 8 + 3], p1 = coefs[o * 8 + 4], p2 = coefs[o * 8 + 5];
    float be = coefs[o * 8 + 6];
    float4 r;
    r.x = fmaxf(fmaf(a0, y0.x, fmaf(a1, y1.x, fmaf(a2, y2.x, fmaf(p0, x0.x, fmaf(p1, x1.x, fmaf(p2, x2.x, be)))))), 0.f);
    r.y = fmaxf(fmaf(a0, y0.y, fmaf(a1, y1.y, fmaf(a2, y2.y, fmaf(p0, x0.y, fmaf(p1, x1.y, fmaf(p2, x2.y, be)))))), 0.f);
    r.z = fmaxf(fmaf(a0, y0.z, fmaf(a1, y1.z, fmaf(a2, y2.z, fmaf(p0, x0.z, fmaf(p1, x1.z, fmaf(p2, x2.z, be)))))), 0.f);
    r.w = fmaxf(fmaf(a0, y0.w, fmaf(a1, y1.w, fmaf(a2, y2.w, fmaf(p0, x0.w, fmaf(p1, x1.w, fmaf(p2, x2.w, be)))))), 0.f);
    *(float4*)(ob + (size_t)o * TV + tq) = r;
  }
}

extern "C" void kernel_launch(void* const* d_in, const int* in_sizes, int n_in,
                              void* d_out, int out_size, void* d_ws, size_t ws_size,
                              hipStream_t stream)
{
  (void)in_sizes; (void)n_in; (void)out_size; (void)ws_size;
  const float* x     = (const float*)d_in[0];
  const float* w1    = (const float*)d_in[1];
  const float* b1    = (const float*)d_in[2];
  const float* w2    = (const float*)d_in[3];
  const float* b2    = (const float*)d_in[4];
  const float* cw    = (const float*)d_in[5];
  const float* cb    = (const float*)d_in[6];
  const float* cg_   = (const float*)d_in[7];
  const float* cbeta = (const float*)d_in[8];
  const float* PA    = (const float*)d_in[9];
  const float* alpha = (const float*)d_in[10];
  const float* c2w   = (const float*)d_in[11];
  const float* c2b   = (const float*)d_in[12];
  const float* bng   = (const float*)d_in[13];
  const float* bnb   = (const float*)d_in[14];
  const float* pw    = (const float*)d_in[15];
  const float* pb    = (const float*)d_in[16];
  const float* pg    = (const float*)d_in[17];
  const float* pbeta = (const float*)d_in[18];
  float* out = (float*)d_out;

  char* ws = (char*)d_ws;
  int*       barr   = (int*)(ws + 0);            // 520 ints -> pad 4096
  long long* accum  = (long long*)(ws + 4096);   // 304 int64 -> pad 8192
  float*     gpart  = (float*)(ws + 8192);       // 512*2688*4 -> ends 5513216
  double*    gramF  = (double*)(ws + 5513216);   // 2652*8 -> ends 5534432
  double*    spart  = (double*)(ws + 5534432);   // 512*5*8 -> ends 5554912 (fallback)
  float*     a3part = (float*)(ws + 5554912);    // 128*289*4 -> ends 5702880 (fallback)

  int maxB = 0;
  hipError_t oe = hipOccupancyMaxActiveBlocksPerMultiprocessor(&maxB, (const void*)fused, 256, 0);
  bool coop = (oe == hipSuccess) && (maxB >= 2);

  if (coop) {
    hipLaunchKernelGGL(kinit, dim3(1), dim3(256), 0, stream, barr, accum);
    void* args[] = {
      (void*)&x, (void*)&w1, (void*)&b1, (void*)&w2, (void*)&b2,
      (void*)&cw, (void*)&cb, (void*)&cg_, (void*)&cbeta,
      (void*)&PA, (void*)&alpha, (void*)&c2w, (void*)&c2b,
      (void*)&bng, (void*)&bnb, (void*)&pw, (void*)&pb, (void*)&pg, (void*)&pbeta,
      (void*)&out, (void*)&barr, (void*)&accum, (void*)&gpart, (void*)&gramF
    };
    hipError_t le = hipLaunchCooperativeKernel((const void*)fused, dim3(NB), dim3(256), args, 0, stream);
    if (le == hipSuccess) return;
    coop = false;   // fall through to the verified 3-kernel path
  }

  hipLaunchKernelGGL(fk1, dim3(512), dim3(256), 0, stream,
                     x, w1, b1, w2, b2, cw, cb, spart, gpart);
  hipLaunchKernelGGL(fk2, dim3(2, Nn), dim3(256), 0, stream,
                     x, spart, gpart, w1, b1, w2, b2, cw, cb, cg_, cbeta, a3part, gramF);
  hipLaunchKernelGGL(fk3, dim3(512), dim3(256), 0, stream,
                     x, PA, alpha, a3part, gramF, c2w, c2b, bng, bnb,
                     pw, pb, pg, pbeta, out);
}

// Round 10
// 107.367 us; speedup vs baseline: 2.7286x; 2.2900x over previous
//
#include <hip/hip_runtime.h>

constexpr int Nn = 64, Tt = 512, Vv = 17, Oo = 64;
constexpr int TV  = Tt * Vv;      // 8704
constexpr int CTV = 3 * TV;       // 26112
constexpr float EPSf = 1e-5f;
constexpr int NG   = 51;          // gram dim
constexpr int GSTR = 2688;        // gpart per-block stride (floats)
constexpr int NGE  = 2652;        // 51*51 + 51
constexpr int BTV  = 1088;        // 64*17

__device__ inline int div17(int v) { return (int)(((unsigned)v * 61681u) >> 20); }

__device__ inline double wred(double v) {
#pragma unroll
  for (int o = 32; o > 0; o >>= 1) v += __shfl_down(v, o, 64);
  return v;
}

// ---------------------------------------------------------------------------
// K1: 512 blocks. s-stat partials (5 f64) + 51x51 xr-gram partials + col means.
__global__ void __launch_bounds__(256) k1(
    const float* __restrict__ x,
    const float* __restrict__ w1, const float* __restrict__ b1,
    const float* __restrict__ w2, const float* __restrict__ b2,
    const float* __restrict__ cw, const float* __restrict__ cb,
    double* __restrict__ spart, float* __restrict__ gpart)
{
  __shared__ float wr[64 * 56];
  __shared__ float xsA[64 * 51];
  __shared__ double dred[4][5];
  const int tid = threadIdx.x, bid = blockIdx.x;
  const int n = bid >> 3, ch = bid & 7;
  {
    const float4* src = (const float4*)(x + (size_t)bid * 3264);
    float4* dst = (float4*)xsA;
    for (int i = tid; i < 816; i += 256) dst[i] = src[i];
  }
#pragma unroll
  for (int c = 0; c < 3; ++c) {
    const float4* src = (const float4*)(x + (size_t)n * CTV + (size_t)c * TV + ch * BTV);
    for (int i = tid; i < 272; i += 256) {
      float4 v = src[i];
      int p = i * 4;
      float vv[4] = { v.x, v.y, v.z, v.w };
#pragma unroll
      for (int k = 0; k < 4; ++k) {
        int pp = p + k; int t = div17(pp), u = pp - t * 17;
        wr[t * 56 + c * 17 + u] = vv[k];
      }
    }
  }
  for (int i = tid; i < 64 * 5; i += 256) { int t = i / 5, j = 51 + (i - t * 5); wr[t * 56 + j] = 0.f; }
  __syncthreads();
  float u1[3], u2[3];
#pragma unroll
  for (int k = 0; k < 3; ++k) {
    float s1 = 0.f, s2 = 0.f;
#pragma unroll
    for (int c = 0; c < 3; ++c) { s1 += cw[c] * w1[c * 3 + k]; s2 += cw[c] * w2[c * 3 + k]; }
    u1[k] = s1; u2[k] = s2;
  }
  float d1 = 0.f, d2 = 0.f;
#pragma unroll
  for (int c = 0; c < 3; ++c) { d1 += b1[c] * cw[c]; d2 += b2[c] * cw[c]; }
  const float bb = cb[0];
  if (tid < 49) {
    const int r8 = (tid / 7) * 8, c8 = (tid - (tid / 7) * 7) * 8;
    float acc[8][8];
#pragma unroll
    for (int a = 0; a < 8; ++a)
#pragma unroll
      for (int b = 0; b < 8; ++b) acc[a][b] = 0.f;
    for (int t = 0; t < 64; ++t) {
      const float* row = &wr[t * 56];
      float4 ra0 = *(const float4*)(row + r8), ra1 = *(const float4*)(row + r8 + 4);
      float4 cb0 = *(const float4*)(row + c8), cb1 = *(const float4*)(row + c8 + 4);
      float ae[8] = { ra0.x, ra0.y, ra0.z, ra0.w, ra1.x, ra1.y, ra1.z, ra1.w };
      float be[8] = { cb0.x, cb0.y, cb0.z, cb0.w, cb1.x, cb1.y, cb1.z, cb1.w };
#pragma unroll
      for (int a = 0; a < 8; ++a)
#pragma unroll
        for (int b = 0; b < 8; ++b) acc[a][b] = fmaf(ae[a], be[b], acc[a][b]);
    }
    float* gp = gpart + (size_t)bid * GSTR;
#pragma unroll
    for (int a = 0; a < 8; ++a) {
      int j = r8 + a;
      if (j < NG) {
#pragma unroll
        for (int b = 0; b < 8; ++b) {
          int jp = c8 + b;
          if (jp < NG) gp[j * NG + jp] = acc[a][b];
        }
      }
    }
  }
  double st[5] = {0, 0, 0, 0, 0};
  if (tid >= 64 && tid < 128) {
    const float* rp = &xsA[(tid - 64) * 51];
    float A = 0.f, G = 0.f, Q1 = 0.f, Q2 = 0.f;
#pragma unroll
    for (int v = 0; v < 17; ++v) {
      float x0 = rp[v * 3], x1 = rp[v * 3 + 1], x2 = rp[v * 3 + 2];
      float va1 = fmaf(x0, u1[0], fmaf(x1, u1[1], fmaf(x2, u1[2], d1)));
      float va2 = fmaf(x0, u2[0], fmaf(x1, u2[1], fmaf(x2, u2[2], d2)));
      float g = bb - va2;
      A += va1; G += g;
      Q1 = fmaf(va1, va1, Q1); Q2 = fmaf(g, g, Q2);
    }
    st[0] = A; st[1] = G; st[2] = Q1; st[3] = Q2; st[4] = (double)A * (double)G;
  }
  if (tid >= 128 && tid < 128 + NG) {
    int j = tid - 128;
    float m = 0.f;
    for (int t = 0; t < 64; ++t) m += wr[t * 56 + j];
    gpart[(size_t)bid * GSTR + NG * NG + j] = m;
  }
  {
    int wv = tid >> 6;
#pragma unroll
    for (int s = 0; s < 5; ++s) { double r = wred(st[s]); if ((tid & 63) == 0) dred[wv][s] = r; }
  }
  __syncthreads();
  if (tid < 5)
    spart[(size_t)bid * 5 + tid] = dred[0][tid] + dred[1][tid] + dred[2][tid] + dred[3][tid];
}

// ---------------------------------------------------------------------------
// K2: 128 blocks (h, n). s-stat global reduce, gram finalize (21/block),
// transposed a1/g staging, b128 segmented a3 chain -> a3part[block][e].
__global__ void __launch_bounds__(256) k2(
    const float* __restrict__ x, const double* __restrict__ spart,
    const float* __restrict__ gpart,
    const float* __restrict__ w1, const float* __restrict__ b1,
    const float* __restrict__ w2, const float* __restrict__ b2,
    const float* __restrict__ cw, const float* __restrict__ cb,
    const float* __restrict__ cg_, const float* __restrict__ cbeta,
    float* __restrict__ a3part, double* __restrict__ gramF)
{
  __shared__ float l1t[17 * 260];
  __shared__ float l2t[17 * 260];
  __shared__ float segsum[289 * 4];
  __shared__ double dred[4][21];
  __shared__ float sfl[2];
  const int tid = threadIdx.x;
  const int h = blockIdx.x, n = blockIdx.y;
  const int jb = n * 2 + h;
  const int t0 = h * 256;
  const int wv = tid >> 6;
  {
    double v5[5];
#pragma unroll
    for (int s = 0; s < 5; ++s)
      v5[s] = spart[(size_t)tid * 5 + s] + spart[(size_t)(tid + 256) * 5 + s];
#pragma unroll
    for (int s = 0; s < 5; ++s) { double r = wred(v5[s]); if ((tid & 63) == 0) dred[wv][s] = r; }
  }
  __syncthreads();
  if (tid == 0) {
    double S[5];
#pragma unroll
    for (int s = 0; s < 5; ++s) S[s] = dred[0][s] + dred[1][s] + dred[2][s] + dred[3][s];
    double cnt = (double)Nn * Tt * Vv * Vv;
    double mean = ((double)Vv * (S[0] + S[1])) / cnt;
    double m2   = ((double)Vv * (S[2] + S[3]) + 2.0 * S[4]) / cnt;
    double var  = m2 - mean * mean;
    double scale = (double)cg_[0] / sqrt(var + (double)EPSf);
    double shift = (double)cbeta[0] + scale * ((double)cb[0] - mean);
    sfl[0] = (float)scale; sfl[1] = (float)(shift - scale * (double)cb[0]);
  }
  __syncthreads();
  {
    int e0 = jb * 21;
    double gv[21];
    const float* g1 = gpart + (size_t)tid * GSTR + e0;
    const float* g2 = gpart + (size_t)(tid + 256) * GSTR + e0;
#pragma unroll
    for (int k = 0; k < 21; ++k) gv[k] = (double)g1[k] + (double)g2[k];
#pragma unroll
    for (int k = 0; k < 21; ++k) { double r = wred(gv[k]); if ((tid & 63) == 0) dred[wv][k] = r; }
    __syncthreads();
    if (tid < 21 && e0 + tid < NGE)
      gramF[e0 + tid] = dred[0][tid] + dred[1][tid] + dred[2][tid] + dred[3][tid];
  }
  float u1[3], u2[3];
#pragma unroll
  for (int k = 0; k < 3; ++k) {
    float s1 = 0.f, s2 = 0.f;
#pragma unroll
    for (int c = 0; c < 3; ++c) { s1 += cw[c] * w1[c * 3 + k]; s2 += cw[c] * w2[c * 3 + k]; }
    u1[k] = s1; u2[k] = s2;
  }
  float d1 = 0.f, d2 = 0.f;
#pragma unroll
  for (int c = 0; c < 3; ++c) { d1 += b1[c] * cw[c]; d2 += b2[c] * cw[c]; }
  const float bb = cb[0];
  const int nst = (h == 0) ? 257 : 256;
  const float* xb = x + ((size_t)(n * Tt + t0)) * 51;
  for (int idx = tid; idx < nst * 17; idx += 256) {
    int r = div17(idx), v = idx - r * 17;
    const float* xp = xb + idx * 3;
    float x0 = xp[0], x1 = xp[1], x2 = xp[2];
    float va1 = fmaf(x0, u1[0], fmaf(x1, u1[1], fmaf(x2, u1[2], d1)));
    float va2 = fmaf(x0, u2[0], fmaf(x1, u2[1], fmaf(x2, u2[2], d2)));
    l1t[v * 260 + r] = va1; l2t[v * 260 + r] = bb - va2;
  }
  __syncthreads();
  {
    const float scale = sfl[0], c0 = sfl[1];
    for (int task = tid; task < 289 * 4; task += 256) {
      int e = task >> 2, s = task & 3;
      int i = div17(e), j = e - i * 17;
      int ts = s * 64;
      bool hasb = !(h == 1 && s == 3);
      const float* J = &l1t[j * 260];
      const float* I = &l2t[i * 260];
      float prev = fmaxf(fmaf(scale, J[ts] + I[ts], c0), 0.f);
      float acc = 0.f;
#pragma unroll 4
      for (int q = 0; q < 16; ++q) {
        float4 a4 = *(const float4*)(J + ts + q * 4);
        float4 b4 = *(const float4*)(I + ts + q * 4);
        float z0 = fmaxf(fmaf(scale, a4.x + b4.x, c0), 0.f);
        float z1 = fmaxf(fmaf(scale, a4.y + b4.y, c0), 0.f);
        float z2 = fmaxf(fmaf(scale, a4.z + b4.z, c0), 0.f);
        float z3 = fmaxf(fmaf(scale, a4.w + b4.w, c0), 0.f);
        if (q > 0) acc += fabsf(z0 - prev);
        acc += fabsf(z1 - z0) + fabsf(z2 - z1) + fabsf(z3 - z2);
        prev = z3;
      }
      if (hasb) {
        float zb = fmaxf(fmaf(scale, J[ts + 64] + I[ts + 64], c0), 0.f);
        acc += fabsf(zb - prev);
      }
      segsum[e * 4 + s] = acc;
    }
  }
  __syncthreads();
  for (int e = tid; e < 289; e += 256) {
    float s = (segsum[e * 4] + segsum[e * 4 + 1]) + (segsum[e * 4 + 2] + segsum[e * 4 + 3]);
    a3part[(size_t)jb * 289 + e] = s;
  }
}

// ---------------------------------------------------------------------------
// K3: 512 blocks x 320 threads. A reduce -> moments -> coefs; y in REGISTERS;
// o-loop with zero LDS data traffic (coefs via 2 broadcast b128 per o).
__global__ void __launch_bounds__(320, 2) k3(
    const float* __restrict__ x,
    const float* __restrict__ PA, const float* __restrict__ alpha,
    const float* __restrict__ a3part, const double* __restrict__ gramF,
    const float* __restrict__ c2w, const float* __restrict__ c2b,
    const float* __restrict__ bng, const float* __restrict__ bnb,
    const float* __restrict__ pw, const float* __restrict__ pb,
    const float* __restrict__ pg, const float* __restrict__ pbeta,
    float* __restrict__ out)
{
  __shared__ float xs[3 * BTV];
  __shared__ float As[289], Bh[289], rsA[17], coefs[512];
  __shared__ double mom[18];
  const int tid = threadIdx.x, bid = blockIdx.x;
  const int n = bid >> 3, ch = bid & 7;
  const int t0c = ch * BTV;

  // P0: stage xs
#pragma unroll
  for (int c = 0; c < 3; ++c) {
    const float4* src = (const float4*)(x + (size_t)n * CTV + (size_t)c * TV + t0c);
    float4* dst = (float4*)(xs + c * BTV);
    for (int i = tid; i < 272; i += 320) dst[i] = src[i];
  }
  // P1: a3 reduce -> A (289 entries, one per thread; coalesced 128-deep)
  if (tid < 289) {
    float acc = 0.f;
#pragma unroll 4
    for (int j = 0; j < 128; ++j) acc += a3part[(size_t)j * 289 + tid];
    As[tid] = fmaf(alpha[tid], acc * (1.0f / Nn), PA[tid]);
  }
  __syncthreads();

  // P2: Bh = A A^T units, row sums; P5a: y into registers (both read As/xs)
  if (tid < 289) {
    int u = div17(tid), up = tid - u * 17;
    float s = 0.f;
#pragma unroll
    for (int v = 0; v < 17; ++v) s = fmaf(As[u * 17 + v], As[up * 17 + v], s);
    Bh[tid] = s;
  }
  if (tid < 17) {
    float s = 0.f;
#pragma unroll
    for (int v = 0; v < 17; ++v) s += As[tid * 17 + v];
    rsA[tid] = s;
  }
  float yreg[3][4], xreg[3][4];
  if (tid < 272) {
    const int i0 = tid * 4;
#pragma unroll
    for (int e = 0; e < 4; ++e) {
      int idx = i0 + e;
      int tr = div17(idx), v = idx - tr * 17;
      float y0 = 0.f, y1 = 0.f, y2 = 0.f;
      const float* r0 = &xs[tr * 17];
      const float* r1 = &xs[BTV + tr * 17];
      const float* r2 = &xs[2 * BTV + tr * 17];
#pragma unroll
      for (int u = 0; u < 17; ++u) {
        float a = As[u * 17 + v];
        y0 = fmaf(r0[u], a, y0); y1 = fmaf(r1[u], a, y1); y2 = fmaf(r2[u], a, y2);
      }
      yreg[0][e] = y0; yreg[1][e] = y1; yreg[2][e] = y2;
      xreg[0][e] = xs[i0 + e]; xreg[1][e] = xs[BTV + i0 + e]; xreg[2][e] = xs[2 * BTV + i0 + e];
    }
  }
  __syncthreads();

  // P3: 18 moments from gramF (global, L2-hot)
  {
    const int pc0[6] = {0, 0, 0, 1, 1, 2};
    const int pc1[6] = {0, 1, 2, 1, 2, 2};
    if (tid < 192) {
      int p = tid >> 5, r = tid & 31;
      int c = pc0[p], cp = pc1[p];
      double s = 0.0;
      for (int k = r; k < 289; k += 32) {
        int u = div17(k), up = k - u * 17;
        s += gramF[(c * 17 + u) * NG + cp * 17 + up] * (double)Bh[k];
      }
#pragma unroll
      for (int off = 16; off > 0; off >>= 1) s += __shfl_down(s, off, 32);
      if (r == 0) mom[3 + p] = s;
    } else if (tid < 198) {
      int p = tid - 192; const int c = pc0[p], cp = pc1[p];
      double s = 0.0;
#pragma unroll
      for (int u = 0; u < 17; ++u) s += gramF[(c * 17 + u) * NG + cp * 17 + u];
      mom[12 + p] = s;
    } else if (tid < 201) {
      int c = tid - 198; double s = 0.0;
#pragma unroll
      for (int u = 0; u < 17; ++u) s += gramF[NG * NG + c * 17 + u] * (double)rsA[u];
      mom[c] = s;
    } else if (tid < 204) {
      int c = tid - 201; double s = 0.0;
#pragma unroll
      for (int u = 0; u < 17; ++u) s += gramF[NG * NG + c * 17 + u];
      mom[9 + c] = s;
    }
  }
  __syncthreads();

  // P4: coefs
  if (tid < 64) {
    int o = tid;
    const double cnt = (double)Nn * Tt * Vv;
    double my0 = mom[0] / cnt, my1 = mom[1] / cnt, my2 = mom[2] / cnt;
    double e00 = mom[3] / cnt, e01 = mom[4] / cnt, e02 = mom[5] / cnt;
    double e11 = mom[6] / cnt, e12 = mom[7] / cnt, e22 = mom[8] / cnt;
    double mx0 = mom[9] / cnt, mx1 = mom[10] / cnt, mx2 = mom[11] / cnt;
    double f00 = mom[12] / cnt, f01 = mom[13] / cnt, f02 = mom[14] / cnt;
    double f11 = mom[15] / cnt, f12 = mom[16] / cnt, f22 = mom[17] / cnt;
    double w0 = c2w[o * 3], w1_ = c2w[o * 3 + 1], w2_ = c2w[o * 3 + 2], bz = c2b[o];
    double wm = w0 * my0 + w1_ * my1 + w2_ * my2, mz = wm + bz;
    double Ez2 = w0 * w0 * e00 + 2 * w0 * w1_ * e01 + 2 * w0 * w2_ * e02
               + w1_ * w1_ * e11 + 2 * w1_ * w2_ * e12 + w2_ * w2_ * e22
               + 2 * bz * wm + bz * bz;
    double sz = (double)bng[o] / sqrt(Ez2 - mz * mz + (double)EPSf);
    double q0 = pw[o * 3], q1 = pw[o * 3 + 1], q2 = pw[o * 3 + 2], bp = pb[o];
    double qm = q0 * mx0 + q1 * mx1 + q2 * mx2, mp = qm + bp;
    double Ep2 = q0 * q0 * f00 + 2 * q0 * q1 * f01 + 2 * q0 * q2 * f02
               + q1 * q1 * f11 + 2 * q1 * q2 * f12 + q2 * q2 * f22
               + 2 * bp * qm + bp * bp;
    double sp = (double)pg[o] / sqrt(Ep2 - mp * mp + (double)EPSf);
    coefs[o * 8 + 0] = (float)(sz * w0); coefs[o * 8 + 1] = (float)(sz * w1_); coefs[o * 8 + 2] = (float)(sz * w2_);
    coefs[o * 8 + 3] = (float)(sp * q0); coefs[o * 8 + 4] = (float)(sp * q1); coefs[o * 8 + 5] = (float)(sp * q2);
    coefs[o * 8 + 6] = (float)(sz * (bz - mz) + (double)bnb[o] + sp * (bp - mp) + (double)pbeta[o]);
    coefs[o * 8 + 7] = 0.f;
  }
  __syncthreads();

  // P6: o-loop, register-resident y/x; 1 float4 store per o per thread
  if (tid < 272) {
    float* ob = out + (size_t)n * ((size_t)Oo * TV) + t0c + tid * 4;
#pragma unroll 4
    for (int o = 0; o < Oo; ++o) {
      float4 ca = *(const float4*)&coefs[o * 8];
      float4 cbv = *(const float4*)&coefs[o * 8 + 4];
      float4 r;
      r.x = fmaxf(fmaf(ca.x, yreg[0][0], fmaf(ca.y, yreg[1][0], fmaf(ca.z, yreg[2][0],
            fmaf(ca.w, xreg[0][0], fmaf(cbv.x, xreg[1][0], fmaf(cbv.y, xreg[2][0], cbv.z)))))), 0.f);
      r.y = fmaxf(fmaf(ca.x, yreg[0][1], fmaf(ca.y, yreg[1][1], fmaf(ca.z, yreg[2][1],
            fmaf(ca.w, xreg[0][1], fmaf(cbv.x, xreg[1][1], fmaf(cbv.y, xreg[2][1], cbv.z)))))), 0.f);
      r.z = fmaxf(fmaf(ca.x, yreg[0][2], fmaf(ca.y, yreg[1][2], fmaf(ca.z, yreg[2][2],
            fmaf(ca.w, xreg[0][2], fmaf(cbv.x, xreg[1][2], fmaf(cbv.y, xreg[2][2], cbv.z)))))), 0.f);
      r.w = fmaxf(fmaf(ca.x, yreg[0][3], fmaf(ca.y, yreg[1][3], fmaf(ca.z, yreg[2][3],
            fmaf(ca.w, xreg[0][3], fmaf(cbv.x, xreg[1][3], fmaf(cbv.y, xreg[2][3], cbv.z)))))), 0.f);
      *(float4*)(ob + (size_t)o * TV) = r;
    }
  }
}

extern "C" void kernel_launch(void* const* d_in, const int* in_sizes, int n_in,
                              void* d_out, int out_size, void* d_ws, size_t ws_size,
                              hipStream_t stream)
{
  (void)in_sizes; (void)n_in; (void)out_size; (void)ws_size;
  const float* x     = (const float*)d_in[0];
  const float* w1    = (const float*)d_in[1];
  const float* b1    = (const float*)d_in[2];
  const float* w2    = (const float*)d_in[3];
  const float* b2    = (const float*)d_in[4];
  const float* cw    = (const float*)d_in[5];
  const float* cb    = (const float*)d_in[6];
  const float* cg_   = (const float*)d_in[7];
  const float* cbeta = (const float*)d_in[8];
  const float* PA    = (const float*)d_in[9];
  const float* alpha = (const float*)d_in[10];
  const float* c2w   = (const float*)d_in[11];
  const float* c2b   = (const float*)d_in[12];
  const float* bng   = (const float*)d_in[13];
  const float* bnb   = (const float*)d_in[14];
  const float* pw    = (const float*)d_in[15];
  const float* pb    = (const float*)d_in[16];
  const float* pg    = (const float*)d_in[17];
  const float* pbeta = (const float*)d_in[18];
  float* out = (float*)d_out;

  char* ws = (char*)d_ws;
  double* spart  = (double*)(ws + 0);          // 512*5*8     = 20480
  float*  gpart  = (float*)(ws + 20480);       // 512*2688*4  = 5505024 -> 5525504
  float*  a3part = (float*)(ws + 5525504);     // 128*289*4   = 147968  -> 5673472
  double* gramF  = (double*)(ws + 5673472);    // 2652*8      = 21216   -> 5694688

  hipLaunchKernelGGL(k1, dim3(512), dim3(256), 0, stream,
                     x, w1, b1, w2, b2, cw, cb, spart, gpart);
  hipLaunchKernelGGL(k2, dim3(2, Nn), dim3(256), 0, stream,
                     x, spart, gpart, w1, b1, w2, b2, cw, cb, cg_, cbeta, a3part, gramF);
  hipLaunchKernelGGL(k3, dim3(512), dim3(320), 0, stream,
                     x, PA, alpha, a3part, gramF, c2w, c2b, bng, bnb,
                     pw, pb, pg, pbeta, out);
}

// Round 11
// 87.862 us; speedup vs baseline: 3.3343x; 1.2220x over previous
//
#include <hip/hip_runtime.h>

constexpr int Nn = 64, Tt = 512, Vv = 17, Oo = 64;
constexpr int TV  = Tt * Vv;      // 8704
constexpr int CTV = 3 * TV;       // 26112
constexpr float EPSf = 1e-5f;
constexpr int NG   = 51;          // gram dim
constexpr int GSTR = 2688;        // gpart per-block stride (floats)
constexpr int NGE  = 2652;        // 51*51 + 51
constexpr int BTV  = 1088;        // 64*17

__device__ inline int div17(int v) { return (int)(((unsigned)v * 61681u) >> 20); }
__device__ inline int div272(int v) { return (int)(((unsigned)v * 15421u) >> 22); }  // exact for v<4608

__device__ inline double wred(double v) {
#pragma unroll
  for (int o = 32; o > 0; o >>= 1) v += __shfl_down(v, o, 64);
  return v;
}

// ---------------------------------------------------------------------------
// K1: 512 blocks. s-stat partials (5 f64) + 51x51 xr-gram partials + col means.
__global__ void __launch_bounds__(256) k1(
    const float* __restrict__ x,
    const float* __restrict__ w1, const float* __restrict__ b1,
    const float* __restrict__ w2, const float* __restrict__ b2,
    const float* __restrict__ cw, const float* __restrict__ cb,
    double* __restrict__ spart, float* __restrict__ gpart)
{
  __shared__ float wr[64 * 56];
  __shared__ float xsA[64 * 51];
  __shared__ double dred[4][5];
  const int tid = threadIdx.x, bid = blockIdx.x;
  const int n = bid >> 3, ch = bid & 7;
  {
    const float4* src = (const float4*)(x + (size_t)bid * 3264);
    float4* dst = (float4*)xsA;
    for (int i = tid; i < 816; i += 256) dst[i] = src[i];
  }
#pragma unroll
  for (int c = 0; c < 3; ++c) {
    const float4* src = (const float4*)(x + (size_t)n * CTV + (size_t)c * TV + ch * BTV);
    for (int i = tid; i < 272; i += 256) {
      float4 v = src[i];
      int p = i * 4;
      float vv[4] = { v.x, v.y, v.z, v.w };
#pragma unroll
      for (int k = 0; k < 4; ++k) {
        int pp = p + k; int t = div17(pp), u = pp - t * 17;
        wr[t * 56 + c * 17 + u] = vv[k];
      }
    }
  }
  for (int i = tid; i < 64 * 5; i += 256) { int t = i / 5, j = 51 + (i - t * 5); wr[t * 56 + j] = 0.f; }
  __syncthreads();
  float u1[3], u2[3];
#pragma unroll
  for (int k = 0; k < 3; ++k) {
    float s1 = 0.f, s2 = 0.f;
#pragma unroll
    for (int c = 0; c < 3; ++c) { s1 += cw[c] * w1[c * 3 + k]; s2 += cw[c] * w2[c * 3 + k]; }
    u1[k] = s1; u2[k] = s2;
  }
  float d1 = 0.f, d2 = 0.f;
#pragma unroll
  for (int c = 0; c < 3; ++c) { d1 += b1[c] * cw[c]; d2 += b2[c] * cw[c]; }
  const float bb = cb[0];
  if (tid < 49) {
    const int r8 = (tid / 7) * 8, c8 = (tid - (tid / 7) * 7) * 8;
    float acc[8][8];
#pragma unroll
    for (int a = 0; a < 8; ++a)
#pragma unroll
      for (int b = 0; b < 8; ++b) acc[a][b] = 0.f;
    for (int t = 0; t < 64; ++t) {
      const float* row = &wr[t * 56];
      float4 ra0 = *(const float4*)(row + r8), ra1 = *(const float4*)(row + r8 + 4);
      float4 cb0 = *(const float4*)(row + c8), cb1 = *(const float4*)(row + c8 + 4);
      float ae[8] = { ra0.x, ra0.y, ra0.z, ra0.w, ra1.x, ra1.y, ra1.z, ra1.w };
      float be[8] = { cb0.x, cb0.y, cb0.z, cb0.w, cb1.x, cb1.y, cb1.z, cb1.w };
#pragma unroll
      for (int a = 0; a < 8; ++a)
#pragma unroll
        for (int b = 0; b < 8; ++b) acc[a][b] = fmaf(ae[a], be[b], acc[a][b]);
    }
    float* gp = gpart + (size_t)bid * GSTR;
#pragma unroll
    for (int a = 0; a < 8; ++a) {
      int j = r8 + a;
      if (j < NG) {
#pragma unroll
        for (int b = 0; b < 8; ++b) {
          int jp = c8 + b;
          if (jp < NG) gp[j * NG + jp] = acc[a][b];
        }
      }
    }
  }
  double st[5] = {0, 0, 0, 0, 0};
  if (tid >= 64 && tid < 128) {
    const float* rp = &xsA[(tid - 64) * 51];
    float A = 0.f, G = 0.f, Q1 = 0.f, Q2 = 0.f;
#pragma unroll
    for (int v = 0; v < 17; ++v) {
      float x0 = rp[v * 3], x1 = rp[v * 3 + 1], x2 = rp[v * 3 + 2];
      float va1 = fmaf(x0, u1[0], fmaf(x1, u1[1], fmaf(x2, u1[2], d1)));
      float va2 = fmaf(x0, u2[0], fmaf(x1, u2[1], fmaf(x2, u2[2], d2)));
      float g = bb - va2;
      A += va1; G += g;
      Q1 = fmaf(va1, va1, Q1); Q2 = fmaf(g, g, Q2);
    }
    st[0] = A; st[1] = G; st[2] = Q1; st[3] = Q2; st[4] = (double)A * (double)G;
  }
  if (tid >= 128 && tid < 128 + NG) {
    int j = tid - 128;
    float m = 0.f;
    for (int t = 0; t < 64; ++t) m += wr[t * 56 + j];
    gpart[(size_t)bid * GSTR + NG * NG + j] = m;
  }
  {
    int wv = tid >> 6;
#pragma unroll
    for (int s = 0; s < 5; ++s) { double r = wred(st[s]); if ((tid & 63) == 0) dred[wv][s] = r; }
  }
  __syncthreads();
  if (tid < 5)
    spart[(size_t)bid * 5 + tid] = dred[0][tid] + dred[1][tid] + dred[2][tid] + dred[3][tid];
}

// ---------------------------------------------------------------------------
// K2: 128 blocks (h, n). s-stat global reduce, gram finalize (21/block),
// transposed a1/g staging, b128 segmented a3 chain -> a3part[block][e].
__global__ void __launch_bounds__(256) k2(
    const float* __restrict__ x, const double* __restrict__ spart,
    const float* __restrict__ gpart,
    const float* __restrict__ w1, const float* __restrict__ b1,
    const float* __restrict__ w2, const float* __restrict__ b2,
    const float* __restrict__ cw, const float* __restrict__ cb,
    const float* __restrict__ cg_, const float* __restrict__ cbeta,
    float* __restrict__ a3part, double* __restrict__ gramF)
{
  __shared__ float l1t[17 * 260];
  __shared__ float l2t[17 * 260];
  __shared__ float segsum[289 * 4];
  __shared__ double dred[4][21];
  __shared__ float sfl[2];
  const int tid = threadIdx.x;
  const int h = blockIdx.x, n = blockIdx.y;
  const int jb = n * 2 + h;
  const int t0 = h * 256;
  const int wv = tid >> 6;
  {
    double v5[5];
#pragma unroll
    for (int s = 0; s < 5; ++s)
      v5[s] = spart[(size_t)tid * 5 + s] + spart[(size_t)(tid + 256) * 5 + s];
#pragma unroll
    for (int s = 0; s < 5; ++s) { double r = wred(v5[s]); if ((tid & 63) == 0) dred[wv][s] = r; }
  }
  __syncthreads();
  if (tid == 0) {
    double S[5];
#pragma unroll
    for (int s = 0; s < 5; ++s) S[s] = dred[0][s] + dred[1][s] + dred[2][s] + dred[3][s];
    double cnt = (double)Nn * Tt * Vv * Vv;
    double mean = ((double)Vv * (S[0] + S[1])) / cnt;
    double m2   = ((double)Vv * (S[2] + S[3]) + 2.0 * S[4]) / cnt;
    double var  = m2 - mean * mean;
    double scale = (double)cg_[0] / sqrt(var + (double)EPSf);
    double shift = (double)cbeta[0] + scale * ((double)cb[0] - mean);
    sfl[0] = (float)scale; sfl[1] = (float)(shift - scale * (double)cb[0]);
  }
  __syncthreads();
  {
    int e0 = jb * 21;
    double gv[21];
    const float* g1 = gpart + (size_t)tid * GSTR + e0;
    const float* g2 = gpart + (size_t)(tid + 256) * GSTR + e0;
#pragma unroll
    for (int k = 0; k < 21; ++k) gv[k] = (double)g1[k] + (double)g2[k];
#pragma unroll
    for (int k = 0; k < 21; ++k) { double r = wred(gv[k]); if ((tid & 63) == 0) dred[wv][k] = r; }
    __syncthreads();
    if (tid < 21 && e0 + tid < NGE)
      gramF[e0 + tid] = dred[0][tid] + dred[1][tid] + dred[2][tid] + dred[3][tid];
  }
  float u1[3], u2[3];
#pragma unroll
  for (int k = 0; k < 3; ++k) {
    float s1 = 0.f, s2 = 0.f;
#pragma unroll
    for (int c = 0; c < 3; ++c) { s1 += cw[c] * w1[c * 3 + k]; s2 += cw[c] * w2[c * 3 + k]; }
    u1[k] = s1; u2[k] = s2;
  }
  float d1 = 0.f, d2 = 0.f;
#pragma unroll
  for (int c = 0; c < 3; ++c) { d1 += b1[c] * cw[c]; d2 += b2[c] * cw[c]; }
  const float bb = cb[0];
  const int nst = (h == 0) ? 257 : 256;
  const float* xb = x + ((size_t)(n * Tt + t0)) * 51;
  for (int idx = tid; idx < nst * 17; idx += 256) {
    int r = div17(idx), v = idx - r * 17;
    const float* xp = xb + idx * 3;
    float x0 = xp[0], x1 = xp[1], x2 = xp[2];
    float va1 = fmaf(x0, u1[0], fmaf(x1, u1[1], fmaf(x2, u1[2], d1)));
    float va2 = fmaf(x0, u2[0], fmaf(x1, u2[1], fmaf(x2, u2[2], d2)));
    l1t[v * 260 + r] = va1; l2t[v * 260 + r] = bb - va2;
  }
  __syncthreads();
  {
    const float scale = sfl[0], c0 = sfl[1];
    for (int task = tid; task < 289 * 4; task += 256) {
      int e = task >> 2, s = task & 3;
      int i = div17(e), j = e - i * 17;
      int ts = s * 64;
      bool hasb = !(h == 1 && s == 3);
      const float* J = &l1t[j * 260];
      const float* I = &l2t[i * 260];
      float prev = fmaxf(fmaf(scale, J[ts] + I[ts], c0), 0.f);
      float acc = 0.f;
#pragma unroll 4
      for (int q = 0; q < 16; ++q) {
        float4 a4 = *(const float4*)(J + ts + q * 4);
        float4 b4 = *(const float4*)(I + ts + q * 4);
        float z0 = fmaxf(fmaf(scale, a4.x + b4.x, c0), 0.f);
        float z1 = fmaxf(fmaf(scale, a4.y + b4.y, c0), 0.f);
        float z2 = fmaxf(fmaf(scale, a4.z + b4.z, c0), 0.f);
        float z3 = fmaxf(fmaf(scale, a4.w + b4.w, c0), 0.f);
        if (q > 0) acc += fabsf(z0 - prev);
        acc += fabsf(z1 - z0) + fabsf(z2 - z1) + fabsf(z3 - z2);
        prev = z3;
      }
      if (hasb) {
        float zb = fmaxf(fmaf(scale, J[ts + 64] + I[ts + 64], c0), 0.f);
        acc += fabsf(zb - prev);
      }
      segsum[e * 4 + s] = acc;
    }
  }
  __syncthreads();
  for (int e = tid; e < 289; e += 256) {
    float s = (segsum[e * 4] + segsum[e * 4 + 1]) + (segsum[e * 4 + 2] + segsum[e * 4 + 3]);
    a3part[(size_t)jb * 289 + e] = s;
  }
}

// ---------------------------------------------------------------------------
// K3: r6 structure (256 threads, ys in LDS); output loop regrouped as
// 17 q-groups x 4 o's so the 6 y/x b128 loads amortize over 4 stores.
__global__ void __launch_bounds__(256, 2) k3(
    const float* __restrict__ x,
    const float* __restrict__ PA, const float* __restrict__ alpha,
    const float* __restrict__ a3part, const double* __restrict__ gramF,
    const float* __restrict__ c2w, const float* __restrict__ c2b,
    const float* __restrict__ bng, const float* __restrict__ bnb,
    const float* __restrict__ pw, const float* __restrict__ pb,
    const float* __restrict__ pg, const float* __restrict__ pbeta,
    float* __restrict__ out)
{
  __shared__ float xs[3 * BTV], ys[3 * BTV];
  __shared__ float As[289], Bh[289], rsA[17], coefs[512];
  __shared__ double mom[18];
  const int tid = threadIdx.x, bid = blockIdx.x;
  const int n = bid >> 3, ch = bid & 7;
  const int t0c = ch * BTV;

  // P0: stage xs early
#pragma unroll
  for (int c = 0; c < 3; ++c) {
    const float4* src = (const float4*)(x + (size_t)n * CTV + (size_t)c * TV + t0c);
    float4* dst = (float4*)(xs + c * BTV);
    for (int i = tid; i < 272; i += 256) dst[i] = src[i];
  }

  // P1: a3 reduce -> A (coalesced over e)
  for (int e = tid; e < 289; e += 256) {
    float acc = 0.f;
#pragma unroll 4
    for (int j = 0; j < 128; ++j) acc += a3part[(size_t)j * 289 + e];
    As[e] = fmaf(alpha[e], acc * (1.0f / Nn), PA[e]);
  }
  __syncthreads();

  // P2: B = A A^T units, row sums of A
  for (int k = tid; k < 289; k += 256) {
    int u = div17(k), up = k - u * 17;
    float s = 0.f;
#pragma unroll
    for (int v = 0; v < 17; ++v) s = fmaf(As[u * 17 + v], As[up * 17 + v], s);
    Bh[k] = s;
  }
  if (tid < 17) {
    float s = 0.f;
#pragma unroll
    for (int v = 0; v < 17; ++v) s += As[tid * 17 + v];
    rsA[tid] = s;
  }
  __syncthreads();

  // P3: 18 moments from gramF (global, L2-hot)
  {
    const int pc0[6] = {0, 0, 0, 1, 1, 2};
    const int pc1[6] = {0, 1, 2, 1, 2, 2};
    if (tid < 192) {
      int p = tid >> 5, r = tid & 31;
      int c = pc0[p], cp = pc1[p];
      double s = 0.0;
      for (int k = r; k < 289; k += 32) {
        int u = div17(k), up = k - u * 17;
        s += gramF[(c * 17 + u) * NG + cp * 17 + up] * (double)Bh[k];
      }
#pragma unroll
      for (int off = 16; off > 0; off >>= 1) s += __shfl_down(s, off, 32);
      if (r == 0) mom[3 + p] = s;
    } else if (tid < 198) {
      int p = tid - 192; const int c = pc0[p], cp = pc1[p];
      double s = 0.0;
#pragma unroll
      for (int u = 0; u < 17; ++u) s += gramF[(c * 17 + u) * NG + cp * 17 + u];
      mom[12 + p] = s;
    } else if (tid < 201) {
      int c = tid - 198; double s = 0.0;
#pragma unroll
      for (int u = 0; u < 17; ++u) s += gramF[NG * NG + c * 17 + u] * (double)rsA[u];
      mom[c] = s;
    } else if (tid < 204) {
      int c = tid - 201; double s = 0.0;
#pragma unroll
      for (int u = 0; u < 17; ++u) s += gramF[NG * NG + c * 17 + u];
      mom[9 + c] = s;
    }
  }
  __syncthreads();

  // P4: per-o coefs + y chunk into LDS
  if (tid < 64) {
    int o = tid;
    const double cnt = (double)Nn * Tt * Vv;
    double my0 = mom[0] / cnt, my1 = mom[1] / cnt, my2 = mom[2] / cnt;
    double e00 = mom[3] / cnt, e01 = mom[4] / cnt, e02 = mom[5] / cnt;
    double e11 = mom[6] / cnt, e12 = mom[7] / cnt, e22 = mom[8] / cnt;
    double mx0 = mom[9] / cnt, mx1 = mom[10] / cnt, mx2 = mom[11] / cnt;
    double f00 = mom[12] / cnt, f01 = mom[13] / cnt, f02 = mom[14] / cnt;
    double f11 = mom[15] / cnt, f12 = mom[16] / cnt, f22 = mom[17] / cnt;
    double w0 = c2w[o * 3], w1_ = c2w[o * 3 + 1], w2_ = c2w[o * 3 + 2], bz = c2b[o];
    double wm = w0 * my0 + w1_ * my1 + w2_ * my2, mz = wm + bz;
    double Ez2 = w0 * w0 * e00 + 2 * w0 * w1_ * e01 + 2 * w0 * w2_ * e02
               + w1_ * w1_ * e11 + 2 * w1_ * w2_ * e12 + w2_ * w2_ * e22
               + 2 * bz * wm + bz * bz;
    double sz = (double)bng[o] / sqrt(Ez2 - mz * mz + (double)EPSf);
    double q0 = pw[o * 3], q1 = pw[o * 3 + 1], q2 = pw[o * 3 + 2], bp = pb[o];
    double qm = q0 * mx0 + q1 * mx1 + q2 * mx2, mp = qm + bp;
    double Ep2 = q0 * q0 * f00 + 2 * q0 * q1 * f01 + 2 * q0 * q2 * f02
               + q1 * q1 * f11 + 2 * q1 * q2 * f12 + q2 * q2 * f22
               + 2 * bp * qm + bp * bp;
    double sp = (double)pg[o] / sqrt(Ep2 - mp * mp + (double)EPSf);
    coefs[o * 8 + 0] = (float)(sz * w0); coefs[o * 8 + 1] = (float)(sz * w1_); coefs[o * 8 + 2] = (float)(sz * w2_);
    coefs[o * 8 + 3] = (float)(sp * q0); coefs[o * 8 + 4] = (float)(sp * q1); coefs[o * 8 + 5] = (float)(sp * q2);
    coefs[o * 8 + 6] = (float)(sz * (bz - mz) + (double)bnb[o] + sp * (bp - mp) + (double)pbeta[o]);
    coefs[o * 8 + 7] = 0.f;
  }
#pragma unroll
  for (int k = 0; k < 5; ++k) {
    int e = k * 256 + tid;
    if (e < BTV) {
      int tr = div17(e), v = e - tr * 17;
      float y0 = 0.f, y1 = 0.f, y2 = 0.f;
#pragma unroll
      for (int u = 0; u < 17; ++u) {
        float a = As[u * 17 + v];
        y0 = fmaf(xs[tr * 17 + u], a, y0);
        y1 = fmaf(xs[BTV + tr * 17 + u], a, y1);
        y2 = fmaf(xs[2 * BTV + tr * 17 + u], a, y2);
      }
      ys[e] = y0; ys[BTV + e] = y1; ys[2 * BTV + e] = y2;
    }
  }
  __syncthreads();

  // P5: fused output. 17 q-groups x 4 o's: 6 LDS b128 loads amortize 4 stores.
  float* obase = out + (size_t)n * ((size_t)Oo * TV) + t0c;
#pragma unroll 2
  for (int g = 0; g < 17; ++g) {
    int base = g * 256 + tid;          // < 4352
    int o0 = div272(base);
    int tq = (base - o0 * 272) * 4;
    float4 y0 = *(const float4*)&ys[tq];
    float4 y1 = *(const float4*)&ys[BTV + tq];
    float4 y2 = *(const float4*)&ys[2 * BTV + tq];
    float4 x0 = *(const float4*)&xs[tq];
    float4 x1 = *(const float4*)&xs[BTV + tq];
    float4 x2 = *(const float4*)&xs[2 * BTV + tq];
    float* ob = obase + (size_t)o0 * TV + tq;
#pragma unroll
    for (int j = 0; j < 4; ++j) {
      int o = o0 + (j << 4);
      float4 ca = *(const float4*)&coefs[o * 8];
      float4 cv = *(const float4*)&coefs[o * 8 + 4];
      float4 r;
      r.x = fmaxf(fmaf(ca.x, y0.x, fmaf(ca.y, y1.x, fmaf(ca.z, y2.x,
            fmaf(ca.w, x0.x, fmaf(cv.x, x1.x, fmaf(cv.y, x2.x, cv.z)))))), 0.f);
      r.y = fmaxf(fmaf(ca.x, y0.y, fmaf(ca.y, y1.y, fmaf(ca.z, y2.y,
            fmaf(ca.w, x0.y, fmaf(cv.x, x1.y, fmaf(cv.y, x2.y, cv.z)))))), 0.f);
      r.z = fmaxf(fmaf(ca.x, y0.z, fmaf(ca.y, y1.z, fmaf(ca.z, y2.z,
            fmaf(ca.w, x0.z, fmaf(cv.x, x1.z, fmaf(cv.y, x2.z, cv.z)))))), 0.f);
      r.w = fmaxf(fmaf(ca.x, y0.w, fmaf(ca.y, y1.w, fmaf(ca.z, y2.w,
            fmaf(ca.w, x0.w, fmaf(cv.x, x1.w, fmaf(cv.y, x2.w, cv.z)))))), 0.f);
      *(float4*)(ob + (size_t)(j << 4) * TV) = r;
    }
  }
}

extern "C" void kernel_launch(void* const* d_in, const int* in_sizes, int n_in,
                              void* d_out, int out_size, void* d_ws, size_t ws_size,
                              hipStream_t stream)
{
  (void)in_sizes; (void)n_in; (void)out_size; (void)ws_size;
  const float* x     = (const float*)d_in[0];
  const float* w1    = (const float*)d_in[1];
  const float* b1    = (const float*)d_in[2];
  const float* w2    = (const float*)d_in[3];
  const float* b2    = (const float*)d_in[4];
  const float* cw    = (const float*)d_in[5];
  const float* cb    = (const float*)d_in[6];
  const float* cg_   = (const float*)d_in[7];
  const float* cbeta = (const float*)d_in[8];
  const float* PA    = (const float*)d_in[9];
  const float* alpha = (const float*)d_in[10];
  const float* c2w   = (const float*)d_in[11];
  const float* c2b   = (const float*)d_in[12];
  const float* bng   = (const float*)d_in[13];
  const float* bnb   = (const float*)d_in[14];
  const float* pw    = (const float*)d_in[15];
  const float* pb    = (const float*)d_in[16];
  const float* pg    = (const float*)d_in[17];
  const float* pbeta = (const float*)d_in[18];
  float* out = (float*)d_out;

  char* ws = (char*)d_ws;
  double* spart  = (double*)(ws + 0);          // 512*5*8     = 20480
  float*  gpart  = (float*)(ws + 20480);       // 512*2688*4  = 5505024 -> 5525504
  float*  a3part = (float*)(ws + 5525504);     // 128*289*4   = 147968  -> 5673472
  double* gramF  = (double*)(ws + 5673472);    // 2652*8      = 21216   -> 5694688

  hipLaunchKernelGGL(k1, dim3(512), dim3(256), 0, stream,
                     x, w1, b1, w2, b2, cw, cb, spart, gpart);
  hipLaunchKernelGGL(k2, dim3(2, Nn), dim3(256), 0, stream,
                     x, spart, gpart, w1, b1, w2, b2, cw, cb, cg_, cbeta, a3part, gramF);
  hipLaunchKernelGGL(k3, dim3(512), dim3(256), 0, stream,
                     x, PA, alpha, a3part, gramF, c2w, c2b, bng, bnb,
                     pw, pb, pg, pbeta, out);
}

// Round 12
// 82.900 us; speedup vs baseline: 3.5339x; 1.0599x over previous
//
#include <hip/hip_runtime.h>

constexpr int Nn = 64, Tt = 512, Vv = 17, Oo = 64;
constexpr int TV  = Tt * Vv;      // 8704
constexpr int CTV = 3 * TV;       // 26112
constexpr float EPSf = 1e-5f;
constexpr int NG   = 51;          // gram dim
constexpr int GSTR = 2688;        // gpart per-block stride (floats)
constexpr int NGE  = 2652;        // 51*51 + 51
constexpr int BTV  = 1088;        // 64*17

__device__ inline int div17(int v) { return (int)(((unsigned)v * 61681u) >> 20); }
__device__ inline int div272(int v) { return (int)(((unsigned)v * 15421u) >> 22); }  // exact for v<4608

__device__ inline double wred(double v) {
#pragma unroll
  for (int o = 32; o > 0; o >>= 1) v += __shfl_down(v, o, 64);
  return v;
}

// ---------------------------------------------------------------------------
// K1: 512 blocks. 4-wave-parallel 51x51 gram partials + col means + s-stats.
__global__ void __launch_bounds__(256) k1(
    const float* __restrict__ x,
    const float* __restrict__ w1, const float* __restrict__ b1,
    const float* __restrict__ w2, const float* __restrict__ b2,
    const float* __restrict__ cw, const float* __restrict__ cb,
    double* __restrict__ spart, float* __restrict__ gpart)
{
  __shared__ float wr[64 * 56];        // 14336 B
  __shared__ float xsA[64 * 51];       // 13056 B
  __shared__ float gpw[4][2601];       // 41616 B: per-wave gram partials
  __shared__ double dred[4][5];
  const int tid = threadIdx.x, bid = blockIdx.x;
  const int n = bid >> 3, ch = bid & 7;
  const int wv = tid >> 6, lane = tid & 63;

  // stage xsA: contiguous chunk
  {
    const float4* src = (const float4*)(x + (size_t)bid * 3264);
    float4* dst = (float4*)xsA;
    for (int i = tid; i < 816; i += 256) dst[i] = src[i];
  }
  // stage wr (xr view), padded rows of 56
#pragma unroll
  for (int c = 0; c < 3; ++c) {
    const float4* src = (const float4*)(x + (size_t)n * CTV + (size_t)c * TV + ch * BTV);
    for (int i = tid; i < 272; i += 256) {
      float4 v = src[i];
      int p = i * 4;
      float vv[4] = { v.x, v.y, v.z, v.w };
#pragma unroll
      for (int k = 0; k < 4; ++k) {
        int pp = p + k; int t = div17(pp), u = pp - t * 17;
        wr[t * 56 + c * 17 + u] = vv[k];
      }
    }
  }
  for (int i = tid; i < 64 * 5; i += 256) { int t = i / 5, j = 51 + (i - t * 5); wr[t * 56 + j] = 0.f; }
  __syncthreads();

  // folded weights
  float u1[3], u2[3];
#pragma unroll
  for (int k = 0; k < 3; ++k) {
    float s1 = 0.f, s2 = 0.f;
#pragma unroll
    for (int c = 0; c < 3; ++c) { s1 += cw[c] * w1[c * 3 + k]; s2 += cw[c] * w2[c * 3 + k]; }
    u1[k] = s1; u2[k] = s2;
  }
  float d1 = 0.f, d2 = 0.f;
#pragma unroll
  for (int c = 0; c < 3; ++c) { d1 += b1[c] * cw[c]; d2 += b2[c] * cw[c]; }
  const float bb = cb[0];

  // gram: every wave handles 16 t-rows, lanes 0..48 own an 8x8 tile
  if (lane < 49) {
    const int r8 = (lane / 7) * 8, c8 = (lane - (lane / 7) * 7) * 8;
    const int tbeg = wv * 16;
    float acc[8][8];
#pragma unroll
    for (int a = 0; a < 8; ++a)
#pragma unroll
      for (int b = 0; b < 8; ++b) acc[a][b] = 0.f;
    for (int t = tbeg; t < tbeg + 16; ++t) {
      const float* row = &wr[t * 56];
      float4 ra0 = *(const float4*)(row + r8), ra1 = *(const float4*)(row + r8 + 4);
      float4 cb0 = *(const float4*)(row + c8), cb1 = *(const float4*)(row + c8 + 4);
      float ae[8] = { ra0.x, ra0.y, ra0.z, ra0.w, ra1.x, ra1.y, ra1.z, ra1.w };
      float be[8] = { cb0.x, cb0.y, cb0.z, cb0.w, cb1.x, cb1.y, cb1.z, cb1.w };
#pragma unroll
      for (int a = 0; a < 8; ++a)
#pragma unroll
        for (int b = 0; b < 8; ++b) acc[a][b] = fmaf(ae[a], be[b], acc[a][b]);
    }
    float* gw = gpw[wv];
#pragma unroll
    for (int a = 0; a < 8; ++a) {
      int j = r8 + a;
      if (j < NG) {
#pragma unroll
        for (int b = 0; b < 8; ++b) {
          int jp = c8 + b;
          if (jp < NG) gw[j * NG + jp] = acc[a][b];
        }
      }
    }
  }
  __syncthreads();

  // reduce 4 gram partials -> gpart
  {
    float* gp = gpart + (size_t)bid * GSTR;
    for (int e = tid; e < NG * NG; e += 256)
      gp[e] = (gpw[0][e] + gpw[1][e]) + (gpw[2][e] + gpw[3][e]);
  }
  // col means from wr
  if (tid >= 128 && tid < 128 + NG) {
    int j = tid - 128;
    float m = 0.f;
    for (int t = 0; t < 64; ++t) m += wr[t * 56 + j];
    gpart[(size_t)bid * GSTR + NG * NG + j] = m;
  }
  // s-stats: threads 0..63, one original row each
  double st[5] = {0, 0, 0, 0, 0};
  if (tid < 64) {
    const float* rp = &xsA[tid * 51];
    float A = 0.f, G = 0.f, Q1 = 0.f, Q2 = 0.f;
#pragma unroll
    for (int v = 0; v < 17; ++v) {
      float x0 = rp[v * 3], x1 = rp[v * 3 + 1], x2 = rp[v * 3 + 2];
      float va1 = fmaf(x0, u1[0], fmaf(x1, u1[1], fmaf(x2, u1[2], d1)));
      float va2 = fmaf(x0, u2[0], fmaf(x1, u2[1], fmaf(x2, u2[2], d2)));
      float g = bb - va2;
      A += va1; G += g;
      Q1 = fmaf(va1, va1, Q1); Q2 = fmaf(g, g, Q2);
    }
    st[0] = A; st[1] = G; st[2] = Q1; st[3] = Q2; st[4] = (double)A * (double)G;
  }
#pragma unroll
  for (int s = 0; s < 5; ++s) { double r = wred(st[s]); if (lane == 0) dred[wv][s] = r; }
  __syncthreads();
  if (tid < 5)
    spart[(size_t)bid * 5 + tid] = dred[0][tid] + dred[1][tid] + dred[2][tid] + dred[3][tid];
}

// ---------------------------------------------------------------------------
// K2: 128 blocks (h, n). s-stat global reduce, gram finalize (21/block),
// transposed a1/g staging, b128 segmented a3 chain -> a3part[block][e].
__global__ void __launch_bounds__(256) k2(
    const float* __restrict__ x, const double* __restrict__ spart,
    const float* __restrict__ gpart,
    const float* __restrict__ w1, const float* __restrict__ b1,
    const float* __restrict__ w2, const float* __restrict__ b2,
    const float* __restrict__ cw, const float* __restrict__ cb,
    const float* __restrict__ cg_, const float* __restrict__ cbeta,
    float* __restrict__ a3part, double* __restrict__ gramF)
{
  __shared__ float l1t[17 * 260];
  __shared__ float l2t[17 * 260];
  __shared__ float segsum[289 * 4];
  __shared__ double dred[4][21];
  __shared__ float sfl[2];
  const int tid = threadIdx.x;
  const int h = blockIdx.x, n = blockIdx.y;
  const int jb = n * 2 + h;
  const int t0 = h * 256;
  const int wv = tid >> 6;
  {
    double v5[5];
#pragma unroll
    for (int s = 0; s < 5; ++s)
      v5[s] = spart[(size_t)tid * 5 + s] + spart[(size_t)(tid + 256) * 5 + s];
#pragma unroll
    for (int s = 0; s < 5; ++s) { double r = wred(v5[s]); if ((tid & 63) == 0) dred[wv][s] = r; }
  }
  __syncthreads();
  if (tid == 0) {
    double S[5];
#pragma unroll
    for (int s = 0; s < 5; ++s) S[s] = dred[0][s] + dred[1][s] + dred[2][s] + dred[3][s];
    double cnt = (double)Nn * Tt * Vv * Vv;
    double mean = ((double)Vv * (S[0] + S[1])) / cnt;
    double m2   = ((double)Vv * (S[2] + S[3]) + 2.0 * S[4]) / cnt;
    double var  = m2 - mean * mean;
    double scale = (double)cg_[0] / sqrt(var + (double)EPSf);
    double shift = (double)cbeta[0] + scale * ((double)cb[0] - mean);
    sfl[0] = (float)scale; sfl[1] = (float)(shift - scale * (double)cb[0]);
  }
  __syncthreads();
  {
    int e0 = jb * 21;
    double gv[21];
    const float* g1 = gpart + (size_t)tid * GSTR + e0;
    const float* g2 = gpart + (size_t)(tid + 256) * GSTR + e0;
#pragma unroll
    for (int k = 0; k < 21; ++k) gv[k] = (double)g1[k] + (double)g2[k];
#pragma unroll
    for (int k = 0; k < 21; ++k) { double r = wred(gv[k]); if ((tid & 63) == 0) dred[wv][k] = r; }
    __syncthreads();
    if (tid < 21 && e0 + tid < NGE)
      gramF[e0 + tid] = dred[0][tid] + dred[1][tid] + dred[2][tid] + dred[3][tid];
  }
  float u1[3], u2[3];
#pragma unroll
  for (int k = 0; k < 3; ++k) {
    float s1 = 0.f, s2 = 0.f;
#pragma unroll
    for (int c = 0; c < 3; ++c) { s1 += cw[c] * w1[c * 3 + k]; s2 += cw[c] * w2[c * 3 + k]; }
    u1[k] = s1; u2[k] = s2;
  }
  float d1 = 0.f, d2 = 0.f;
#pragma unroll
  for (int c = 0; c < 3; ++c) { d1 += b1[c] * cw[c]; d2 += b2[c] * cw[c]; }
  const float bb = cb[0];
  const int nst = (h == 0) ? 257 : 256;
  const float* xb = x + ((size_t)(n * Tt + t0)) * 51;
  for (int idx = tid; idx < nst * 17; idx += 256) {
    int r = div17(idx), v = idx - r * 17;
    const float* xp = xb + idx * 3;
    float x0 = xp[0], x1 = xp[1], x2 = xp[2];
    float va1 = fmaf(x0, u1[0], fmaf(x1, u1[1], fmaf(x2, u1[2], d1)));
    float va2 = fmaf(x0, u2[0], fmaf(x1, u2[1], fmaf(x2, u2[2], d2)));
    l1t[v * 260 + r] = va1; l2t[v * 260 + r] = bb - va2;
  }
  __syncthreads();
  {
    const float scale = sfl[0], c0 = sfl[1];
    for (int task = tid; task < 289 * 4; task += 256) {
      int e = task >> 2, s = task & 3;
      int i = div17(e), j = e - i * 17;
      int ts = s * 64;
      bool hasb = !(h == 1 && s == 3);
      const float* J = &l1t[j * 260];
      const float* I = &l2t[i * 260];
      float prev = fmaxf(fmaf(scale, J[ts] + I[ts], c0), 0.f);
      float acc = 0.f;
#pragma unroll 4
      for (int q = 0; q < 16; ++q) {
        float4 a4 = *(const float4*)(J + ts + q * 4);
        float4 b4 = *(const float4*)(I + ts + q * 4);
        float z0 = fmaxf(fmaf(scale, a4.x + b4.x, c0), 0.f);
        float z1 = fmaxf(fmaf(scale, a4.y + b4.y, c0), 0.f);
        float z2 = fmaxf(fmaf(scale, a4.z + b4.z, c0), 0.f);
        float z3 = fmaxf(fmaf(scale, a4.w + b4.w, c0), 0.f);
        if (q > 0) acc += fabsf(z0 - prev);
        acc += fabsf(z1 - z0) + fabsf(z2 - z1) + fabsf(z3 - z2);
        prev = z3;
      }
      if (hasb) {
        float zb = fmaxf(fmaf(scale, J[ts + 64] + I[ts + 64], c0), 0.f);
        acc += fabsf(zb - prev);
      }
      segsum[e * 4 + s] = acc;
    }
  }
  __syncthreads();
  for (int e = tid; e < 289; e += 256) {
    float s = (segsum[e * 4] + segsum[e * 4 + 1]) + (segsum[e * 4 + 2] + segsum[e * 4 + 3]);
    a3part[(size_t)jb * 289 + e] = s;
  }
}

// ---------------------------------------------------------------------------
// K3: r11 structure; P1 rewritten with 4 partial accumulators + deep unroll.
__global__ void __launch_bounds__(256, 2) k3(
    const float* __restrict__ x,
    const float* __restrict__ PA, const float* __restrict__ alpha,
    const float* __restrict__ a3part, const double* __restrict__ gramF,
    const float* __restrict__ c2w, const float* __restrict__ c2b,
    const float* __restrict__ bng, const float* __restrict__ bnb,
    const float* __restrict__ pw, const float* __restrict__ pb,
    const float* __restrict__ pg, const float* __restrict__ pbeta,
    float* __restrict__ out)
{
  __shared__ float xs[3 * BTV], ys[3 * BTV];
  __shared__ float As[289], Bh[289], rsA[17], coefs[512];
  __shared__ double mom[18];
  const int tid = threadIdx.x, bid = blockIdx.x;
  const int n = bid >> 3, ch = bid & 7;
  const int t0c = ch * BTV;

  // P0: stage xs early
#pragma unroll
  for (int c = 0; c < 3; ++c) {
    const float4* src = (const float4*)(x + (size_t)n * CTV + (size_t)c * TV + t0c);
    float4* dst = (float4*)(xs + c * BTV);
    for (int i = tid; i < 272; i += 256) dst[i] = src[i];
  }

  // P1: a3 reduce -> A (coalesced over e; 4 independent partial sums, deep ILP)
  for (int e = tid; e < 289; e += 256) {
    const float* p = a3part + e;
    float a0 = 0.f, a1 = 0.f, a2 = 0.f, a3 = 0.f;
#pragma unroll 8
    for (int j = 0; j < 128; j += 4) {
      a0 += p[(size_t)(j + 0) * 289];
      a1 += p[(size_t)(j + 1) * 289];
      a2 += p[(size_t)(j + 2) * 289];
      a3 += p[(size_t)(j + 3) * 289];
    }
    float acc = (a0 + a1) + (a2 + a3);
    As[e] = fmaf(alpha[e], acc * (1.0f / Nn), PA[e]);
  }
  __syncthreads();

  // P2: B = A A^T units, row sums of A
  for (int k = tid; k < 289; k += 256) {
    int u = div17(k), up = k - u * 17;
    float s = 0.f;
#pragma unroll
    for (int v = 0; v < 17; ++v) s = fmaf(As[u * 17 + v], As[up * 17 + v], s);
    Bh[k] = s;
  }
  if (tid < 17) {
    float s = 0.f;
#pragma unroll
    for (int v = 0; v < 17; ++v) s += As[tid * 17 + v];
    rsA[tid] = s;
  }
  __syncthreads();

  // P3: 18 moments from gramF (global, L2-hot)
  {
    const int pc0[6] = {0, 0, 0, 1, 1, 2};
    const int pc1[6] = {0, 1, 2, 1, 2, 2};
    if (tid < 192) {
      int p = tid >> 5, r = tid & 31;
      int c = pc0[p], cp = pc1[p];
      double s = 0.0;
      for (int k = r; k < 289; k += 32) {
        int u = div17(k), up = k - u * 17;
        s += gramF[(c * 17 + u) * NG + cp * 17 + up] * (double)Bh[k];
      }
#pragma unroll
      for (int off = 16; off > 0; off >>= 1) s += __shfl_down(s, off, 32);
      if (r == 0) mom[3 + p] = s;
    } else if (tid < 198) {
      int p = tid - 192; const int c = pc0[p], cp = pc1[p];
      double s = 0.0;
#pragma unroll
      for (int u = 0; u < 17; ++u) s += gramF[(c * 17 + u) * NG + cp * 17 + u];
      mom[12 + p] = s;
    } else if (tid < 201) {
      int c = tid - 198; double s = 0.0;
#pragma unroll
      for (int u = 0; u < 17; ++u) s += gramF[NG * NG + c * 17 + u] * (double)rsA[u];
      mom[c] = s;
    } else if (tid < 204) {
      int c = tid - 201; double s = 0.0;
#pragma unroll
      for (int u = 0; u < 17; ++u) s += gramF[NG * NG + c * 17 + u];
      mom[9 + c] = s;
    }
  }
  __syncthreads();

  // P4: per-o coefs + y chunk into LDS
  if (tid < 64) {
    int o = tid;
    const double cnt = (double)Nn * Tt * Vv;
    double my0 = mom[0] / cnt, my1 = mom[1] / cnt, my2 = mom[2] / cnt;
    double e00 = mom[3] / cnt, e01 = mom[4] / cnt, e02 = mom[5] / cnt;
    double e11 = mom[6] / cnt, e12 = mom[7] / cnt, e22 = mom[8] / cnt;
    double mx0 = mom[9] / cnt, mx1 = mom[10] / cnt, mx2 = mom[11] / cnt;
    double f00 = mom[12] / cnt, f01 = mom[13] / cnt, f02 = mom[14] / cnt;
    double f11 = mom[15] / cnt, f12 = mom[16] / cnt, f22 = mom[17] / cnt;
    double w0 = c2w[o * 3], w1_ = c2w[o * 3 + 1], w2_ = c2w[o * 3 + 2], bz = c2b[o];
    double wm = w0 * my0 + w1_ * my1 + w2_ * my2, mz = wm + bz;
    double Ez2 = w0 * w0 * e00 + 2 * w0 * w1_ * e01 + 2 * w0 * w2_ * e02
               + w1_ * w1_ * e11 + 2 * w1_ * w2_ * e12 + w2_ * w2_ * e22
               + 2 * bz * wm + bz * bz;
    double sz = (double)bng[o] / sqrt(Ez2 - mz * mz + (double)EPSf);
    double q0 = pw[o * 3], q1 = pw[o * 3 + 1], q2 = pw[o * 3 + 2], bp = pb[o];
    double qm = q0 * mx0 + q1 * mx1 + q2 * mx2, mp = qm + bp;
    double Ep2 = q0 * q0 * f00 + 2 * q0 * q1 * f01 + 2 * q0 * q2 * f02
               + q1 * q1 * f11 + 2 * q1 * q2 * f12 + q2 * q2 * f22
               + 2 * bp * qm + bp * bp;
    double sp = (double)pg[o] / sqrt(Ep2 - mp * mp + (double)EPSf);
    coefs[o * 8 + 0] = (float)(sz * w0); coefs[o * 8 + 1] = (float)(sz * w1_); coefs[o * 8 + 2] = (float)(sz * w2_);
    coefs[o * 8 + 3] = (float)(sp * q0); coefs[o * 8 + 4] = (float)(sp * q1); coefs[o * 8 + 5] = (float)(sp * q2);
    coefs[o * 8 + 6] = (float)(sz * (bz - mz) + (double)bnb[o] + sp * (bp - mp) + (double)pbeta[o]);
    coefs[o * 8 + 7] = 0.f;
  }
#pragma unroll
  for (int k = 0; k < 5; ++k) {
    int e = k * 256 + tid;
    if (e < BTV) {
      int tr = div17(e), v = e - tr * 17;
      float y0 = 0.f, y1 = 0.f, y2 = 0.f;
#pragma unroll
      for (int u = 0; u < 17; ++u) {
        float a = As[u * 17 + v];
        y0 = fmaf(xs[tr * 17 + u], a, y0);
        y1 = fmaf(xs[BTV + tr * 17 + u], a, y1);
        y2 = fmaf(xs[2 * BTV + tr * 17 + u], a, y2);
      }
      ys[e] = y0; ys[BTV + e] = y1; ys[2 * BTV + e] = y2;
    }
  }
  __syncthreads();

  // P5: fused output. 17 q-groups x 4 o's: 6 LDS b128 loads amortize 4 stores.
  float* obase = out + (size_t)n * ((size_t)Oo * TV) + t0c;
#pragma unroll 2
  for (int g = 0; g < 17; ++g) {
    int base = g * 256 + tid;          // < 4352
    int o0 = div272(base);
    int tq = (base - o0 * 272) * 4;
    float4 y0 = *(const float4*)&ys[tq];
    float4 y1 = *(const float4*)&ys[BTV + tq];
    float4 y2 = *(const float4*)&ys[2 * BTV + tq];
    float4 x0 = *(const float4*)&xs[tq];
    float4 x1 = *(const float4*)&xs[BTV + tq];
    float4 x2 = *(const float4*)&xs[2 * BTV + tq];
    float* ob = obase + (size_t)o0 * TV + tq;
#pragma unroll
    for (int j = 0; j < 4; ++j) {
      int o = o0 + (j << 4);
      float4 ca = *(const float4*)&coefs[o * 8];
      float4 cv = *(const float4*)&coefs[o * 8 + 4];
      float4 r;
      r.x = fmaxf(fmaf(ca.x, y0.x, fmaf(ca.y, y1.x, fmaf(ca.z, y2.x,
            fmaf(ca.w, x0.x, fmaf(cv.x, x1.x, fmaf(cv.y, x2.x, cv.z)))))), 0.f);
      r.y = fmaxf(fmaf(ca.x, y0.y, fmaf(ca.y, y1.y, fmaf(ca.z, y2.y,
            fmaf(ca.w, x0.y, fmaf(cv.x, x1.y, fmaf(cv.y, x2.y, cv.z)))))), 0.f);
      r.z = fmaxf(fmaf(ca.x, y0.z, fmaf(ca.y, y1.z, fmaf(ca.z, y2.z,
            fmaf(ca.w, x0.z, fmaf(cv.x, x1.z, fmaf(cv.y, x2.z, cv.z)))))), 0.f);
      r.w = fmaxf(fmaf(ca.x, y0.w, fmaf(ca.y, y1.w, fmaf(ca.z, y2.w,
            fmaf(ca.w, x0.w, fmaf(cv.x, x1.w, fmaf(cv.y, x2.w, cv.z)))))), 0.f);
      *(float4*)(ob + (size_t)(j << 4) * TV) = r;
    }
  }
}

extern "C" void kernel_launch(void* const* d_in, const int* in_sizes, int n_in,
                              void* d_out, int out_size, void* d_ws, size_t ws_size,
                              hipStream_t stream)
{
  (void)in_sizes; (void)n_in; (void)out_size; (void)ws_size;
  const float* x     = (const float*)d_in[0];
  const float* w1    = (const float*)d_in[1];
  const float* b1    = (const float*)d_in[2];
  const float* w2    = (const float*)d_in[3];
  const float* b2    = (const float*)d_in[4];
  const float* cw    = (const float*)d_in[5];
  const float* cb    = (const float*)d_in[6];
  const float* cg_   = (const float*)d_in[7];
  const float* cbeta = (const float*)d_in[8];
  const float* PA    = (const float*)d_in[9];
  const float* alpha = (const float*)d_in[10];
  const float* c2w   = (const float*)d_in[11];
  const float* c2b   = (const float*)d_in[12];
  const float* bng   = (const float*)d_in[13];
  const float* bnb   = (const float*)d_in[14];
  const float* pw    = (const float*)d_in[15];
  const float* pb    = (const float*)d_in[16];
  const float* pg    = (const float*)d_in[17];
  const float* pbeta = (const float*)d_in[18];
  float* out = (float*)d_out;

  char* ws = (char*)d_ws;
  double* spart  = (double*)(ws + 0);          // 512*5*8     = 20480
  float*  gpart  = (float*)(ws + 20480);       // 512*2688*4  = 5505024 -> 5525504
  float*  a3part = (float*)(ws + 5525504);     // 128*289*4   = 147968  -> 5673472
  double* gramF  = (double*)(ws + 5673472);    // 2652*8      = 21216   -> 5694688

  hipLaunchKernelGGL(k1, dim3(512), dim3(256), 0, stream,
                     x, w1, b1, w2, b2, cw, cb, spart, gpart);
  hipLaunchKernelGGL(k2, dim3(2, Nn), dim3(256), 0, stream,
                     x, spart, gpart, w1, b1, w2, b2, cw, cb, cg_, cbeta, a3part, gramF);
  hipLaunchKernelGGL(k3, dim3(512), dim3(256), 0, stream,
                     x, PA, alpha, a3part, gramF, c2w, c2b, bng, bnb,
                     pw, pb, pg, pbeta, out);
}

// Round 13
// 82.790 us; speedup vs baseline: 3.5386x; 1.0013x over previous
//
#include <hip/hip_runtime.h>

constexpr int Nn = 64, Tt = 512, Vv = 17, Oo = 64;
constexpr int TV  = Tt * Vv;      // 8704
constexpr int CTV = 3 * TV;       // 26112
constexpr float EPSf = 1e-5f;
constexpr int NG   = 51;          // gram dim
constexpr int GSTR = 2688;        // gpart per-block stride (floats)
constexpr int NGE  = 2652;        // 51*51 + 51
constexpr int BTV  = 1088;        // 64*17

__device__ inline int div17(int v) { return (int)(((unsigned)v * 61681u) >> 20); }
__device__ inline int div272(int v) { return (int)(((unsigned)v * 15421u) >> 22); }  // exact for v<4608

__device__ inline double wred(double v) {
#pragma unroll
  for (int o = 32; o > 0; o >>= 1) v += __shfl_down(v, o, 64);
  return v;
}

// ---------------------------------------------------------------------------
// K1: 512 blocks. 4-wave-parallel 51x51 gram partials + col means + s-stats.
__global__ void __launch_bounds__(256) k1(
    const float* __restrict__ x,
    const float* __restrict__ w1, const float* __restrict__ b1,
    const float* __restrict__ w2, const float* __restrict__ b2,
    const float* __restrict__ cw, const float* __restrict__ cb,
    double* __restrict__ spart, float* __restrict__ gpart)
{
  __shared__ float wr[64 * 56];        // 14336 B
  __shared__ float xsA[64 * 51];       // 13056 B
  __shared__ float gpw[4][2601];       // 41616 B: per-wave gram partials
  __shared__ double dred[4][5];
  const int tid = threadIdx.x, bid = blockIdx.x;
  const int n = bid >> 3, ch = bid & 7;
  const int wv = tid >> 6, lane = tid & 63;

  {
    const float4* src = (const float4*)(x + (size_t)bid * 3264);
    float4* dst = (float4*)xsA;
    for (int i = tid; i < 816; i += 256) dst[i] = src[i];
  }
#pragma unroll
  for (int c = 0; c < 3; ++c) {
    const float4* src = (const float4*)(x + (size_t)n * CTV + (size_t)c * TV + ch * BTV);
    for (int i = tid; i < 272; i += 256) {
      float4 v = src[i];
      int p = i * 4;
      float vv[4] = { v.x, v.y, v.z, v.w };
#pragma unroll
      for (int k = 0; k < 4; ++k) {
        int pp = p + k; int t = div17(pp), u = pp - t * 17;
        wr[t * 56 + c * 17 + u] = vv[k];
      }
    }
  }
  for (int i = tid; i < 64 * 5; i += 256) { int t = i / 5, j = 51 + (i - t * 5); wr[t * 56 + j] = 0.f; }
  __syncthreads();

  float u1[3], u2[3];
#pragma unroll
  for (int k = 0; k < 3; ++k) {
    float s1 = 0.f, s2 = 0.f;
#pragma unroll
    for (int c = 0; c < 3; ++c) { s1 += cw[c] * w1[c * 3 + k]; s2 += cw[c] * w2[c * 3 + k]; }
    u1[k] = s1; u2[k] = s2;
  }
  float d1 = 0.f, d2 = 0.f;
#pragma unroll
  for (int c = 0; c < 3; ++c) { d1 += b1[c] * cw[c]; d2 += b2[c] * cw[c]; }
  const float bb = cb[0];

  if (lane < 49) {
    const int r8 = (lane / 7) * 8, c8 = (lane - (lane / 7) * 7) * 8;
    const int tbeg = wv * 16;
    float acc[8][8];
#pragma unroll
    for (int a = 0; a < 8; ++a)
#pragma unroll
      for (int b = 0; b < 8; ++b) acc[a][b] = 0.f;
    for (int t = tbeg; t < tbeg + 16; ++t) {
      const float* row = &wr[t * 56];
      float4 ra0 = *(const float4*)(row + r8), ra1 = *(const float4*)(row + r8 + 4);
      float4 cb0 = *(const float4*)(row + c8), cb1 = *(const float4*)(row + c8 + 4);
      float ae[8] = { ra0.x, ra0.y, ra0.z, ra0.w, ra1.x, ra1.y, ra1.z, ra1.w };
      float be[8] = { cb0.x, cb0.y, cb0.z, cb0.w, cb1.x, cb1.y, cb1.z, cb1.w };
#pragma unroll
      for (int a = 0; a < 8; ++a)
#pragma unroll
        for (int b = 0; b < 8; ++b) acc[a][b] = fmaf(ae[a], be[b], acc[a][b]);
    }
    float* gw = gpw[wv];
#pragma unroll
    for (int a = 0; a < 8; ++a) {
      int j = r8 + a;
      if (j < NG) {
#pragma unroll
        for (int b = 0; b < 8; ++b) {
          int jp = c8 + b;
          if (jp < NG) gw[j * NG + jp] = acc[a][b];
        }
      }
    }
  }
  __syncthreads();

  {
    float* gp = gpart + (size_t)bid * GSTR;
    for (int e = tid; e < NG * NG; e += 256)
      gp[e] = (gpw[0][e] + gpw[1][e]) + (gpw[2][e] + gpw[3][e]);
  }
  if (tid >= 128 && tid < 128 + NG) {
    int j = tid - 128;
    float m = 0.f;
    for (int t = 0; t < 64; ++t) m += wr[t * 56 + j];
    gpart[(size_t)bid * GSTR + NG * NG + j] = m;
  }
  double st[5] = {0, 0, 0, 0, 0};
  if (tid < 64) {
    const float* rp = &xsA[tid * 51];
    float A = 0.f, G = 0.f, Q1 = 0.f, Q2 = 0.f;
#pragma unroll
    for (int v = 0; v < 17; ++v) {
      float x0 = rp[v * 3], x1 = rp[v * 3 + 1], x2 = rp[v * 3 + 2];
      float va1 = fmaf(x0, u1[0], fmaf(x1, u1[1], fmaf(x2, u1[2], d1)));
      float va2 = fmaf(x0, u2[0], fmaf(x1, u2[1], fmaf(x2, u2[2], d2)));
      float g = bb - va2;
      A += va1; G += g;
      Q1 = fmaf(va1, va1, Q1); Q2 = fmaf(g, g, Q2);
    }
    st[0] = A; st[1] = G; st[2] = Q1; st[3] = Q2; st[4] = (double)A * (double)G;
  }
#pragma unroll
  for (int s = 0; s < 5; ++s) { double r = wred(st[s]); if (lane == 0) dred[wv][s] = r; }
  __syncthreads();
  if (tid < 5)
    spart[(size_t)bid * 5 + tid] = dred[0][tid] + dred[1][tid] + dred[2][tid] + dred[3][tid];
}

// ---------------------------------------------------------------------------
// K2: 128 blocks (h, n) x 512 threads. Direct 512-partial reductions (one row
// per thread), 2x-parallel staging, chain worst-case 3 tasks/thread.
__global__ void __launch_bounds__(512) k2(
    const float* __restrict__ x, const double* __restrict__ spart,
    const float* __restrict__ gpart,
    const float* __restrict__ w1, const float* __restrict__ b1,
    const float* __restrict__ w2, const float* __restrict__ b2,
    const float* __restrict__ cw, const float* __restrict__ cb,
    const float* __restrict__ cg_, const float* __restrict__ cbeta,
    float* __restrict__ a3part, double* __restrict__ gramF)
{
  __shared__ float l1t[17 * 260];     // 17680 B
  __shared__ float l2t[17 * 260];     // 17680 B
  __shared__ float segsum[289 * 4];   // 4624 B
  __shared__ double dred[8][21];      // 1344 B
  __shared__ float sfl[2];
  const int tid = threadIdx.x;
  const int h = blockIdx.x, n = blockIdx.y;
  const int jb = n * 2 + h;
  const int t0 = h * 256;
  const int wv = tid >> 6;

  // (a) s-stat reduce: one partial row per thread
  {
    double v5[5];
#pragma unroll
    for (int s = 0; s < 5; ++s) v5[s] = spart[(size_t)tid * 5 + s];
#pragma unroll
    for (int s = 0; s < 5; ++s) { double r = wred(v5[s]); if ((tid & 63) == 0) dred[wv][s] = r; }
  }
  __syncthreads();
  if (tid == 0) {
    double S[5];
#pragma unroll
    for (int s = 0; s < 5; ++s) {
      double a = 0.0;
#pragma unroll
      for (int w = 0; w < 8; ++w) a += dred[w][s];
      S[s] = a;
    }
    double cnt = (double)Nn * Tt * Vv * Vv;
    double mean = ((double)Vv * (S[0] + S[1])) / cnt;
    double m2   = ((double)Vv * (S[2] + S[3]) + 2.0 * S[4]) / cnt;
    double var  = m2 - mean * mean;
    double scale = (double)cg_[0] / sqrt(var + (double)EPSf);
    double shift = (double)cbeta[0] + scale * ((double)cb[0] - mean);
    sfl[0] = (float)scale; sfl[1] = (float)(shift - scale * (double)cb[0]);
  }
  __syncthreads();

  // (b) gram finalize: entries [jb*21, jb*21+21), one partial row per thread
  {
    int e0 = jb * 21;
    double gv[21];
    const float* g1 = gpart + (size_t)tid * GSTR + e0;
#pragma unroll
    for (int k = 0; k < 21; ++k) gv[k] = (double)g1[k];
#pragma unroll
    for (int k = 0; k < 21; ++k) { double r = wred(gv[k]); if ((tid & 63) == 0) dred[wv][k] = r; }
    __syncthreads();
    if (tid < 21 && e0 + tid < NGE) {
      double a = 0.0;
#pragma unroll
      for (int w = 0; w < 8; ++w) a += dred[w][tid];
      gramF[e0 + tid] = a;
    }
  }

  // (c) stage a1/g transposed
  float u1[3], u2[3];
#pragma unroll
  for (int k = 0; k < 3; ++k) {
    float s1 = 0.f, s2 = 0.f;
#pragma unroll
    for (int c = 0; c < 3; ++c) { s1 += cw[c] * w1[c * 3 + k]; s2 += cw[c] * w2[c * 3 + k]; }
    u1[k] = s1; u2[k] = s2;
  }
  float d1 = 0.f, d2 = 0.f;
#pragma unroll
  for (int c = 0; c < 3; ++c) { d1 += b1[c] * cw[c]; d2 += b2[c] * cw[c]; }
  const float bb = cb[0];
  const int nst = (h == 0) ? 257 : 256;
  const float* xb = x + ((size_t)(n * Tt + t0)) * 51;
  for (int idx = tid; idx < nst * 17; idx += 512) {
    int r = div17(idx), v = idx - r * 17;
    const float* xp = xb + idx * 3;
    float x0 = xp[0], x1 = xp[1], x2 = xp[2];
    float va1 = fmaf(x0, u1[0], fmaf(x1, u1[1], fmaf(x2, u1[2], d1)));
    float va2 = fmaf(x0, u2[0], fmaf(x1, u2[1], fmaf(x2, u2[2], d2)));
    l1t[v * 260 + r] = va1; l2t[v * 260 + r] = bb - va2;
  }
  __syncthreads();

  // (d) chain: 289 entries x 4 segments of 64, b128 reads
  {
    const float scale = sfl[0], c0 = sfl[1];
    for (int task = tid; task < 289 * 4; task += 512) {
      int e = task >> 2, s = task & 3;
      int i = div17(e), j = e - i * 17;
      int ts = s * 64;
      bool hasb = !(h == 1 && s == 3);
      const float* J = &l1t[j * 260];
      const float* I = &l2t[i * 260];
      float prev = fmaxf(fmaf(scale, J[ts] + I[ts], c0), 0.f);
      float acc = 0.f;
#pragma unroll 4
      for (int q = 0; q < 16; ++q) {
        float4 a4 = *(const float4*)(J + ts + q * 4);
        float4 b4 = *(const float4*)(I + ts + q * 4);
        float z0 = fmaxf(fmaf(scale, a4.x + b4.x, c0), 0.f);
        float z1 = fmaxf(fmaf(scale, a4.y + b4.y, c0), 0.f);
        float z2 = fmaxf(fmaf(scale, a4.z + b4.z, c0), 0.f);
        float z3 = fmaxf(fmaf(scale, a4.w + b4.w, c0), 0.f);
        if (q > 0) acc += fabsf(z0 - prev);
        acc += fabsf(z1 - z0) + fabsf(z2 - z1) + fabsf(z3 - z2);
        prev = z3;
      }
      if (hasb) {
        float zb = fmaxf(fmaf(scale, J[ts + 64] + I[ts + 64], c0), 0.f);
        acc += fabsf(zb - prev);
      }
      segsum[e * 4 + s] = acc;
    }
  }
  __syncthreads();

  // (e) segment sum -> a3part[jb][e]
  for (int e = tid; e < 289; e += 512) {
    float s = (segsum[e * 4] + segsum[e * 4 + 1]) + (segsum[e * 4 + 2] + segsum[e * 4 + 3]);
    a3part[(size_t)jb * 289 + e] = s;
  }
}

// ---------------------------------------------------------------------------
// K3: r12 verbatim.
__global__ void __launch_bounds__(256, 2) k3(
    const float* __restrict__ x,
    const float* __restrict__ PA, const float* __restrict__ alpha,
    const float* __restrict__ a3part, const double* __restrict__ gramF,
    const float* __restrict__ c2w, const float* __restrict__ c2b,
    const float* __restrict__ bng, const float* __restrict__ bnb,
    const float* __restrict__ pw, const float* __restrict__ pb,
    const float* __restrict__ pg, const float* __restrict__ pbeta,
    float* __restrict__ out)
{
  __shared__ float xs[3 * BTV], ys[3 * BTV];
  __shared__ float As[289], Bh[289], rsA[17], coefs[512];
  __shared__ double mom[18];
  const int tid = threadIdx.x, bid = blockIdx.x;
  const int n = bid >> 3, ch = bid & 7;
  const int t0c = ch * BTV;

#pragma unroll
  for (int c = 0; c < 3; ++c) {
    const float4* src = (const float4*)(x + (size_t)n * CTV + (size_t)c * TV + t0c);
    float4* dst = (float4*)(xs + c * BTV);
    for (int i = tid; i < 272; i += 256) dst[i] = src[i];
  }

  for (int e = tid; e < 289; e += 256) {
    const float* p = a3part + e;
    float a0 = 0.f, a1 = 0.f, a2 = 0.f, a3 = 0.f;
#pragma unroll 8
    for (int j = 0; j < 128; j += 4) {
      a0 += p[(size_t)(j + 0) * 289];
      a1 += p[(size_t)(j + 1) * 289];
      a2 += p[(size_t)(j + 2) * 289];
      a3 += p[(size_t)(j + 3) * 289];
    }
    float acc = (a0 + a1) + (a2 + a3);
    As[e] = fmaf(alpha[e], acc * (1.0f / Nn), PA[e]);
  }
  __syncthreads();

  for (int k = tid; k < 289; k += 256) {
    int u = div17(k), up = k - u * 17;
    float s = 0.f;
#pragma unroll
    for (int v = 0; v < 17; ++v) s = fmaf(As[u * 17 + v], As[up * 17 + v], s);
    Bh[k] = s;
  }
  if (tid < 17) {
    float s = 0.f;
#pragma unroll
    for (int v = 0; v < 17; ++v) s += As[tid * 17 + v];
    rsA[tid] = s;
  }
  __syncthreads();

  {
    const int pc0[6] = {0, 0, 0, 1, 1, 2};
    const int pc1[6] = {0, 1, 2, 1, 2, 2};
    if (tid < 192) {
      int p = tid >> 5, r = tid & 31;
      int c = pc0[p], cp = pc1[p];
      double s = 0.0;
      for (int k = r; k < 289; k += 32) {
        int u = div17(k), up = k - u * 17;
        s += gramF[(c * 17 + u) * NG + cp * 17 + up] * (double)Bh[k];
      }
#pragma unroll
      for (int off = 16; off > 0; off >>= 1) s += __shfl_down(s, off, 32);
      if (r == 0) mom[3 + p] = s;
    } else if (tid < 198) {
      int p = tid - 192; const int c = pc0[p], cp = pc1[p];
      double s = 0.0;
#pragma unroll
      for (int u = 0; u < 17; ++u) s += gramF[(c * 17 + u) * NG + cp * 17 + u];
      mom[12 + p] = s;
    } else if (tid < 201) {
      int c = tid - 198; double s = 0.0;
#pragma unroll
      for (int u = 0; u < 17; ++u) s += gramF[NG * NG + c * 17 + u] * (double)rsA[u];
      mom[c] = s;
    } else if (tid < 204) {
      int c = tid - 201; double s = 0.0;
#pragma unroll
      for (int u = 0; u < 17; ++u) s += gramF[NG * NG + c * 17 + u];
      mom[9 + c] = s;
    }
  }
  __syncthreads();

  if (tid < 64) {
    int o = tid;
    const double cnt = (double)Nn * Tt * Vv;
    double my0 = mom[0] / cnt, my1 = mom[1] / cnt, my2 = mom[2] / cnt;
    double e00 = mom[3] / cnt, e01 = mom[4] / cnt, e02 = mom[5] / cnt;
    double e11 = mom[6] / cnt, e12 = mom[7] / cnt, e22 = mom[8] / cnt;
    double mx0 = mom[9] / cnt, mx1 = mom[10] / cnt, mx2 = mom[11] / cnt;
    double f00 = mom[12] / cnt, f01 = mom[13] / cnt, f02 = mom[14] / cnt;
    double f11 = mom[15] / cnt, f12 = mom[16] / cnt, f22 = mom[17] / cnt;
    double w0 = c2w[o * 3], w1_ = c2w[o * 3 + 1], w2_ = c2w[o * 3 + 2], bz = c2b[o];
    double wm = w0 * my0 + w1_ * my1 + w2_ * my2, mz = wm + bz;
    double Ez2 = w0 * w0 * e00 + 2 * w0 * w1_ * e01 + 2 * w0 * w2_ * e02
               + w1_ * w1_ * e11 + 2 * w1_ * w2_ * e12 + w2_ * w2_ * e22
               + 2 * bz * wm + bz * bz;
    double sz = (double)bng[o] / sqrt(Ez2 - mz * mz + (double)EPSf);
    double q0 = pw[o * 3], q1 = pw[o * 3 + 1], q2 = pw[o * 3 + 2], bp = pb[o];
    double qm = q0 * mx0 + q1 * mx1 + q2 * mx2, mp = qm + bp;
    double Ep2 = q0 * q0 * f00 + 2 * q0 * q1 * f01 + 2 * q0 * q2 * f02
               + q1 * q1 * f11 + 2 * q1 * q2 * f12 + q2 * q2 * f22
               + 2 * bp * qm + bp * bp;
    double sp = (double)pg[o] / sqrt(Ep2 - mp * mp + (double)EPSf);
    coefs[o * 8 + 0] = (float)(sz * w0); coefs[o * 8 + 1] = (float)(sz * w1_); coefs[o * 8 + 2] = (float)(sz * w2_);
    coefs[o * 8 + 3] = (float)(sp * q0); coefs[o * 8 + 4] = (float)(sp * q1); coefs[o * 8 + 5] = (float)(sp * q2);
    coefs[o * 8 + 6] = (float)(sz * (bz - mz) + (double)bnb[o] + sp * (bp - mp) + (double)pbeta[o]);
    coefs[o * 8 + 7] = 0.f;
  }
#pragma unroll
  for (int k = 0; k < 5; ++k) {
    int e = k * 256 + tid;
    if (e < BTV) {
      int tr = div17(e), v = e - tr * 17;
      float y0 = 0.f, y1 = 0.f, y2 = 0.f;
#pragma unroll
      for (int u = 0; u < 17; ++u) {
        float a = As[u * 17 + v];
        y0 = fmaf(xs[tr * 17 + u], a, y0);
        y1 = fmaf(xs[BTV + tr * 17 + u], a, y1);
        y2 = fmaf(xs[2 * BTV + tr * 17 + u], a, y2);
      }
      ys[e] = y0; ys[BTV + e] = y1; ys[2 * BTV + e] = y2;
    }
  }
  __syncthreads();

  float* obase = out + (size_t)n * ((size_t)Oo * TV) + t0c;
#pragma unroll 2
  for (int g = 0; g < 17; ++g) {
    int base = g * 256 + tid;          // < 4352
    int o0 = div272(base);
    int tq = (base - o0 * 272) * 4;
    float4 y0 = *(const float4*)&ys[tq];
    float4 y1 = *(const float4*)&ys[BTV + tq];
    float4 y2 = *(const float4*)&ys[2 * BTV + tq];
    float4 x0 = *(const float4*)&xs[tq];
    float4 x1 = *(const float4*)&xs[BTV + tq];
    float4 x2 = *(const float4*)&xs[2 * BTV + tq];
    float* ob = obase + (size_t)o0 * TV + tq;
#pragma unroll
    for (int j = 0; j < 4; ++j) {
      int o = o0 + (j << 4);
      float4 ca = *(const float4*)&coefs[o * 8];
      float4 cv = *(const float4*)&coefs[o * 8 + 4];
      float4 r;
      r.x = fmaxf(fmaf(ca.x, y0.x, fmaf(ca.y, y1.x, fmaf(ca.z, y2.x,
            fmaf(ca.w, x0.x, fmaf(cv.x, x1.x, fmaf(cv.y, x2.x, cv.z)))))), 0.f);
      r.y = fmaxf(fmaf(ca.x, y0.y, fmaf(ca.y, y1.y, fmaf(ca.z, y2.y,
            fmaf(ca.w, x0.y, fmaf(cv.x, x1.y, fmaf(cv.y, x2.y, cv.z)))))), 0.f);
      r.z = fmaxf(fmaf(ca.x, y0.z, fmaf(ca.y, y1.z, fmaf(ca.z, y2.z,
            fmaf(ca.w, x0.z, fmaf(cv.x, x1.z, fmaf(cv.y, x2.z, cv.z)))))), 0.f);
      r.w = fmaxf(fmaf(ca.x, y0.w, fmaf(ca.y, y1.w, fmaf(ca.z, y2.w,
            fmaf(ca.w, x0.w, fmaf(cv.x, x1.w, fmaf(cv.y, x2.w, cv.z)))))), 0.f);
      *(float4*)(ob + (size_t)(j << 4) * TV) = r;
    }
  }
}

extern "C" void kernel_launch(void* const* d_in, const int* in_sizes, int n_in,
                              void* d_out, int out_size, void* d_ws, size_t ws_size,
                              hipStream_t stream)
{
  (void)in_sizes; (void)n_in; (void)out_size; (void)ws_size;
  const float* x     = (const float*)d_in[0];
  const float* w1    = (const float*)d_in[1];
  const float* b1    = (const float*)d_in[2];
  const float* w2    = (const float*)d_in[3];
  const float* b2    = (const float*)d_in[4];
  const float* cw    = (const float*)d_in[5];
  const float* cb    = (const float*)d_in[6];
  const float* cg_   = (const float*)d_in[7];
  const float* cbeta = (const float*)d_in[8];
  const float* PA    = (const float*)d_in[9];
  const float* alpha = (const float*)d_in[10];
  const float* c2w   = (const float*)d_in[11];
  const float* c2b   = (const float*)d_in[12];
  const float* bng   = (const float*)d_in[13];
  const float* bnb   = (const float*)d_in[14];
  const float* pw    = (const float*)d_in[15];
  const float* pb    = (const float*)d_in[16];
  const float* pg    = (const float*)d_in[17];
  const float* pbeta = (const float*)d_in[18];
  float* out = (float*)d_out;

  char* ws = (char*)d_ws;
  double* spart  = (double*)(ws + 0);          // 512*5*8     = 20480
  float*  gpart  = (float*)(ws + 20480);       // 512*2688*4  = 5505024 -> 5525504
  float*  a3part = (float*)(ws + 5525504);     // 128*289*4   = 147968  -> 5673472
  double* gramF  = (double*)(ws + 5673472);    // 2652*8      = 21216   -> 5694688

  hipLaunchKernelGGL(k1, dim3(512), dim3(256), 0, stream,
                     x, w1, b1, w2, b2, cw, cb, spart, gpart);
  hipLaunchKernelGGL(k2, dim3(2, Nn), dim3(512), 0, stream,
                     x, spart, gpart, w1, b1, w2, b2, cw, cb, cg_, cbeta, a3part, gramF);
  hipLaunchKernelGGL(k3, dim3(512), dim3(256), 0, stream,
                     x, PA, alpha, a3part, gramF, c2w, c2b, bng, bnb,
                     pw, pb, pg, pbeta, out);
}